// Round 1
// baseline (627.951 us; speedup 1.0000x reference)
//
#include <hip/hip_runtime.h>

#define B_DIM 4
#define C_DIM 256
#define N_DIM 4096
#define CT_DIM 256
#define SPLIT 2

typedef float f32x4 __attribute__((ext_vector_type(4)));
typedef short bf16x8 __attribute__((ext_vector_type(8)));

static __device__ __forceinline__ short f2bf(float f) {
  unsigned int u = __builtin_bit_cast(unsigned int, f);
  u += 0x7fffu + ((u >> 16) & 1u);
  return (short)(u >> 16);
}

static __device__ __forceinline__ bf16x8 ldW8(const float* __restrict__ p) {
  f32x4 a = *reinterpret_cast<const f32x4*>(p);
  f32x4 b = *reinterpret_cast<const f32x4*>(p + 4);
  bf16x8 o;
  o[0] = f2bf(a[0]); o[1] = f2bf(a[1]); o[2] = f2bf(a[2]); o[3] = f2bf(a[3]);
  o[4] = f2bf(b[0]); o[5] = f2bf(b[1]); o[6] = f2bf(b[2]); o[7] = f2bf(b[3]);
  return o;
}

#define MFMA(a, b, c) __builtin_amdgcn_mfma_f32_16x16x32_bf16((a), (b), (c), 0, 0, 0)

// LDS row stride for 256 bf16 elems + pad; 272*2=544 B (16B multiple)
#define LDS_STRIDE 272

// Kernel 1: projections. grid = B * (N/64), block = 256.
// Computes qb[b][n][ct], kb[b][n][ct] (= k^T), vtb[b][ct][n], xT[b][n][c] all bf16.
__global__ __launch_bounds__(256) void proj_kernel(
    const float* __restrict__ x, const float* __restrict__ Wq,
    const float* __restrict__ Wk, const float* __restrict__ Wv,
    short* __restrict__ qb, short* __restrict__ kb,
    short* __restrict__ vtb, short* __restrict__ xT) {
  __shared__ short xt[64 * LDS_STRIDE];
  const int b = blockIdx.x >> 6;
  const int n0 = (blockIdx.x & 63) * 64;
  const int tid = threadIdx.x;
  const int w = tid >> 6;
  const int l = tid & 63;
  const int lr = l & 15;
  const int lg = l >> 4;

  // stage x tile (C=256 x 64 n) into LDS transposed as bf16
  {
    const float* xb = x + (size_t)b * C_DIM * N_DIM + n0;
    const int n = tid & 63;
    const int cbase = tid >> 6;
#pragma unroll 4
    for (int it = 0; it < 64; ++it) {
      const int c = it * 4 + cbase;
      xt[n * LDS_STRIDE + c] = f2bf(xb[(size_t)c * N_DIM + n]);
    }
  }
  __syncthreads();

  // write xT to global (coalesced, from LDS)
  {
    const int nn = tid >> 5;
    const int cc = (tid & 31) * 8;
#pragma unroll
    for (int it = 0; it < 8; ++it) {
      const int row = it * 8 + nn;
      bf16x8 v = *reinterpret_cast<const bf16x8*>(&xt[row * LDS_STRIDE + cc]);
      *reinterpret_cast<bf16x8*>(&xT[((size_t)(b * N_DIM) + n0 + row) * C_DIM + cc]) = v;
    }
  }

  f32x4 zz; zz[0] = 0.f; zz[1] = 0.f; zz[2] = 0.f; zz[3] = 0.f;

  // q and k passes: output (n, ct). wave w owns ct range [w*64, w*64+64)
  for (int pass = 0; pass < 2; ++pass) {
    const float* W = pass ? Wk : Wq;
    short* dst = pass ? kb : qb;
    f32x4 acc[4][4];
#pragma unroll
    for (int cs = 0; cs < 4; ++cs)
#pragma unroll
      for (int ns = 0; ns < 4; ++ns) acc[cs][ns] = zz;
#pragma unroll
    for (int kk = 0; kk < 8; ++kk) {
      bf16x8 af[4], bf[4];
#pragma unroll
      for (int ns = 0; ns < 4; ++ns)
        af[ns] = *reinterpret_cast<const bf16x8*>(&xt[(ns * 16 + lr) * LDS_STRIDE + kk * 32 + lg * 8]);
#pragma unroll
      for (int cs = 0; cs < 4; ++cs)
        bf[cs] = ldW8(&W[(size_t)(w * 64 + cs * 16 + lr) * C_DIM + kk * 32 + lg * 8]);
#pragma unroll
      for (int cs = 0; cs < 4; ++cs)
#pragma unroll
        for (int ns = 0; ns < 4; ++ns) acc[cs][ns] = MFMA(af[ns], bf[cs], acc[cs][ns]);
    }
#pragma unroll
    for (int cs = 0; cs < 4; ++cs)
#pragma unroll
      for (int ns = 0; ns < 4; ++ns)
#pragma unroll
        for (int r = 0; r < 4; ++r) {
          const int n = n0 + ns * 16 + lg * 4 + r;
          const int ct = w * 64 + cs * 16 + lr;
          dst[((size_t)(b * N_DIM) + n) * CT_DIM + ct] = f2bf(acc[cs][ns][r]);
        }
  }

  // v pass: output (ct, n) so the global write of v^T is coalesced
  {
    f32x4 acc[4][4];
#pragma unroll
    for (int as = 0; as < 4; ++as)
#pragma unroll
      for (int ns = 0; ns < 4; ++ns) acc[as][ns] = zz;
#pragma unroll
    for (int kk = 0; kk < 8; ++kk) {
      bf16x8 af[4], bf[4];
#pragma unroll
      for (int as = 0; as < 4; ++as)
        af[as] = ldW8(&Wv[(size_t)(w * 64 + as * 16 + lr) * C_DIM + kk * 32 + lg * 8]);
#pragma unroll
      for (int ns = 0; ns < 4; ++ns)
        bf[ns] = *reinterpret_cast<const bf16x8*>(&xt[(ns * 16 + lr) * LDS_STRIDE + kk * 32 + lg * 8]);
#pragma unroll
      for (int as = 0; as < 4; ++as)
#pragma unroll
        for (int ns = 0; ns < 4; ++ns) acc[as][ns] = MFMA(af[as], bf[ns], acc[as][ns]);
    }
#pragma unroll
    for (int as = 0; as < 4; ++as)
#pragma unroll
      for (int ns = 0; ns < 4; ++ns)
#pragma unroll
        for (int r = 0; r < 4; ++r) {
          const int ct = w * 64 + as * 16 + lg * 4 + r;
          const int n = n0 + ns * 16 + lr;
          vtb[((size_t)(b * CT_DIM) + ct) * N_DIM + n] = f2bf(acc[as][ns][r]);
        }
  }
}

// Kernel 2: flash attention partials. grid = B * (N/64) * SPLIT, block = 256 (4 waves).
// Each wave owns 16 q rows; split s covers keys [s*2048, (s+1)*2048).
__global__ __launch_bounds__(256) void attn_kernel(
    const short* __restrict__ qb, const short* __restrict__ kb,
    const short* __restrict__ vtb, float* __restrict__ Opart,
    float* __restrict__ mpart, float* __restrict__ lpart) {
  const int bid = blockIdx.x;
  const int s = bid & (SPLIT - 1);
  const int qt = (bid >> 1) & 63;
  const int b = bid >> 7;
  const int tid = threadIdx.x;
  const int w = tid >> 6;
  const int l = tid & 63;
  const int lr = l & 15;
  const int lg = l >> 4;
  const int nbase = qt * 64 + w * 16;

  __shared__ short plds[4][16][80];  // per-wave private P tile (16 rows x 64 cols, stride 80)

  // Q fragments live in registers for the whole kernel
  bf16x8 qf[8];
  {
    const short* qrow = qb + ((size_t)(b * N_DIM) + nbase + lr) * CT_DIM + lg * 8;
#pragma unroll
    for (int kk = 0; kk < 8; ++kk)
      qf[kk] = *reinterpret_cast<const bf16x8*>(qrow + kk * 32);
  }

  f32x4 zz; zz[0] = 0.f; zz[1] = 0.f; zz[2] = 0.f; zz[3] = 0.f;
  f32x4 o[16];
#pragma unroll
  for (int cs = 0; cs < 16; ++cs) o[cs] = zz;
  float m_r[4], l_r[4];
#pragma unroll
  for (int r = 0; r < 4; ++r) { m_r[r] = -1e30f; l_r[r] = 0.f; }

  const int m_begin = s * (N_DIM / SPLIT);
  const int m_end = m_begin + (N_DIM / SPLIT);

  for (int m0 = m_begin; m0 < m_end; m0 += 64) {
    // S = Q K^T for 16 q rows x 64 keys
    f32x4 sacc[4];
#pragma unroll
    for (int mt = 0; mt < 4; ++mt) sacc[mt] = zz;
#pragma unroll
    for (int mt = 0; mt < 4; ++mt) {
      const short* krow = kb + ((size_t)(b * N_DIM) + m0 + mt * 16 + lr) * CT_DIM + lg * 8;
#pragma unroll
      for (int kk = 0; kk < 8; ++kk)
        sacc[mt] = MFMA(qf[kk], *reinterpret_cast<const bf16x8*>(krow + kk * 32), sacc[mt]);
    }

    // online softmax (rows spread as row = lg*4 + r, cols = mt*16 + lr)
    float sc[4][4];
#pragma unroll
    for (int mt = 0; mt < 4; ++mt)
#pragma unroll
      for (int r = 0; r < 4; ++r) sc[mt][r] = sacc[mt][r] * 0.0625f;

    float rmax[4];
#pragma unroll
    for (int r = 0; r < 4; ++r)
      rmax[r] = fmaxf(fmaxf(sc[0][r], sc[1][r]), fmaxf(sc[2][r], sc[3][r]));
#pragma unroll
    for (int d = 1; d < 16; d <<= 1)
#pragma unroll
      for (int r = 0; r < 4; ++r) rmax[r] = fmaxf(rmax[r], __shfl_xor(rmax[r], d));

    float corr[4], rsum[4];
#pragma unroll
    for (int r = 0; r < 4; ++r) {
      const float mnew = fmaxf(m_r[r], rmax[r]);
      corr[r] = __expf(m_r[r] - mnew);
      m_r[r] = mnew;
      rsum[r] = 0.f;
    }
#pragma unroll
    for (int mt = 0; mt < 4; ++mt)
#pragma unroll
      for (int r = 0; r < 4; ++r) {
        const float p = __expf(sc[mt][r] - m_r[r]);
        sc[mt][r] = p;
        rsum[r] += p;
      }
#pragma unroll
    for (int d = 1; d < 16; d <<= 1)
#pragma unroll
      for (int r = 0; r < 4; ++r) rsum[r] += __shfl_xor(rsum[r], d);
#pragma unroll
    for (int r = 0; r < 4; ++r) l_r[r] = l_r[r] * corr[r] + rsum[r];

    // rescale O
#pragma unroll
    for (int cs = 0; cs < 16; ++cs)
#pragma unroll
      for (int r = 0; r < 4; ++r) o[cs][r] *= corr[r];

    // P -> LDS (per-wave private, no barrier needed)
#pragma unroll
    for (int mt = 0; mt < 4; ++mt)
#pragma unroll
      for (int r = 0; r < 4; ++r)
        plds[w][lg * 4 + r][mt * 16 + lr] = f2bf(sc[mt][r]);

    // O += P V
#pragma unroll
    for (int kk2 = 0; kk2 < 2; ++kk2) {
      bf16x8 pa = *reinterpret_cast<const bf16x8*>(&plds[w][lr][kk2 * 32 + lg * 8]);
      const short* vbase = vtb + (size_t)b * CT_DIM * N_DIM + m0 + kk2 * 32 + lg * 8;
#pragma unroll
      for (int cs = 0; cs < 16; ++cs)
        o[cs] = MFMA(pa, *reinterpret_cast<const bf16x8*>(vbase + (size_t)(cs * 16 + lr) * N_DIM), o[cs]);
    }
  }

  // write partials
  float* obase = Opart + (size_t)(s * B_DIM + b) * N_DIM * CT_DIM;
#pragma unroll
  for (int cs = 0; cs < 16; ++cs)
#pragma unroll
    for (int r = 0; r < 4; ++r) {
      const int n = nbase + lg * 4 + r;
      obase[(size_t)n * CT_DIM + cs * 16 + lr] = o[cs][r];
    }
  if (lr == 0) {
#pragma unroll
    for (int r = 0; r < 4; ++r) {
      const int n = nbase + lg * 4 + r;
      mpart[(size_t)(s * B_DIM + b) * N_DIM + n] = m_r[r];
      lpart[(size_t)(s * B_DIM + b) * N_DIM + n] = l_r[r];
    }
  }
}

// Kernel 3: combine split partials -> ctxT bf16 (B, N, CT). grid = B*N, block = 256.
__global__ __launch_bounds__(256) void combine_kernel(
    const float* __restrict__ Opart, const float* __restrict__ mpart,
    const float* __restrict__ lpart, short* __restrict__ ctxT) {
  const int b = blockIdx.x >> 12;
  const int n = blockIdx.x & (N_DIM - 1);
  const int ct = threadIdx.x;
  const size_t row = (size_t)b * N_DIM + n;
  const size_t sstride = (size_t)B_DIM * N_DIM;
  const float m0 = mpart[row], m1 = mpart[sstride + row];
  const float mm = fmaxf(m0, m1);
  const float e0 = __expf(m0 - mm), e1 = __expf(m1 - mm);
  const float l0 = lpart[row], l1 = lpart[sstride + row];
  const float inv = 1.0f / (l0 * e0 + l1 * e1);
  const float o0 = Opart[row * CT_DIM + ct];
  const float o1 = Opart[sstride * CT_DIM + row * CT_DIM + ct];
  ctxT[row * CT_DIM + ct] = f2bf((o0 * e0 + o1 * e1) * inv);
}

// Kernel 4: out[b][o][n] = Wo[:, :256] @ ctx + Wo[:, 256:] @ x. grid = B*(N/64), block=256.
__global__ __launch_bounds__(256) void out_kernel(
    const float* __restrict__ Wo, const short* __restrict__ ctxT,
    const short* __restrict__ xT, float* __restrict__ out) {
  const int b = blockIdx.x >> 6;
  const int n0 = (blockIdx.x & 63) * 64;
  const int tid = threadIdx.x;
  const int w = tid >> 6;
  const int l = tid & 63;
  const int lr = l & 15;
  const int lg = l >> 4;

  f32x4 zz; zz[0] = 0.f; zz[1] = 0.f; zz[2] = 0.f; zz[3] = 0.f;
  f32x4 acc[4][4];  // [os][ns]; wave w owns o range [w*64, w*64+64)
#pragma unroll
  for (int os = 0; os < 4; ++os)
#pragma unroll
    for (int ns = 0; ns < 4; ++ns) acc[os][ns] = zz;

#pragma unroll 4
  for (int kk = 0; kk < 16; ++kk) {
    const short* src = (kk < 8) ? ctxT : xT;
    const int c = (kk & 7) * 32 + lg * 8;
    bf16x8 bf[4], af[4];
#pragma unroll
    for (int ns = 0; ns < 4; ++ns)
      bf[ns] = *reinterpret_cast<const bf16x8*>(&src[((size_t)(b * N_DIM) + n0 + ns * 16 + lr) * 256 + c]);
#pragma unroll
    for (int os = 0; os < 4; ++os)
      af[os] = ldW8(&Wo[(size_t)(w * 64 + os * 16 + lr) * 512 + kk * 32 + lg * 8]);
#pragma unroll
    for (int os = 0; os < 4; ++os)
#pragma unroll
      for (int ns = 0; ns < 4; ++ns) acc[os][ns] = MFMA(af[os], bf[ns], acc[os][ns]);
  }

#pragma unroll
  for (int os = 0; os < 4; ++os)
#pragma unroll
    for (int ns = 0; ns < 4; ++ns)
#pragma unroll
      for (int r = 0; r < 4; ++r) {
        const int oo = w * 64 + os * 16 + lg * 4 + r;
        const int n = n0 + ns * 16 + lr;
        out[((size_t)(b * C_DIM) + oo) * N_DIM + n] = acc[os][ns][r];
      }
}

extern "C" void kernel_launch(void* const* d_in, const int* in_sizes, int n_in,
                              void* d_out, int out_size, void* d_ws, size_t ws_size,
                              hipStream_t stream) {
  const float* x = (const float*)d_in[0];
  const float* Wq = (const float*)d_in[1];
  const float* Wk = (const float*)d_in[2];
  const float* Wv = (const float*)d_in[3];
  const float* Wo = (const float*)d_in[4];
  float* out = (float*)d_out;

  char* ws = (char*)d_ws;
  const size_t SZ_BNCT = (size_t)B_DIM * N_DIM * CT_DIM * sizeof(short);  // 8 MB
  short* qb   = (short*)(ws);
  short* kb   = (short*)(ws + SZ_BNCT);
  short* vtb  = (short*)(ws + 2 * SZ_BNCT);
  short* xT   = (short*)(ws + 3 * SZ_BNCT);
  short* ctxT = (short*)(ws + 4 * SZ_BNCT);
  float* Opart = (float*)(ws + 5 * SZ_BNCT);  // SPLIT * B * N * CT fp32 = 32 MB
  float* mpart = (float*)(ws + 5 * SZ_BNCT + (size_t)SPLIT * B_DIM * N_DIM * CT_DIM * 4);
  float* lpart = mpart + (size_t)SPLIT * B_DIM * N_DIM;

  proj_kernel<<<B_DIM * (N_DIM / 64), 256, 0, stream>>>(x, Wq, Wk, Wv, qb, kb, vtb, xT);
  attn_kernel<<<B_DIM * (N_DIM / 64) * SPLIT, 256, 0, stream>>>(qb, kb, vtb, Opart, mpart, lpart);
  combine_kernel<<<B_DIM * N_DIM, 256, 0, stream>>>(Opart, mpart, lpart, ctxT);
  out_kernel<<<B_DIM * (N_DIM / 64), 256, 0, stream>>>(Wo, ctxT, xT, out);
}

// Round 2
// 303.728 us; speedup vs baseline: 2.0675x; 2.0675x over previous
//
#include <hip/hip_runtime.h>

#define B_DIM 4
#define C_DIM 256
#define N_DIM 4096
#define CT_DIM 256
#define SPLIT 4

typedef float f32x4 __attribute__((ext_vector_type(4)));
typedef short bf16x8 __attribute__((ext_vector_type(8)));
typedef unsigned int u32;

static __device__ __forceinline__ short f2bf(float f) {
  u32 u = __builtin_bit_cast(u32, f);
  u += 0x7fffu + ((u >> 16) & 1u);
  return (short)(u >> 16);
}
static __device__ __forceinline__ float bf2f(short s) {
  u32 u = ((u32)(unsigned short)s) << 16;
  return __builtin_bit_cast(float, u);
}

static __device__ __forceinline__ bf16x8 ldW8(const float* __restrict__ p) {
  f32x4 a = *reinterpret_cast<const f32x4*>(p);
  f32x4 b = *reinterpret_cast<const f32x4*>(p + 4);
  bf16x8 o;
  o[0] = f2bf(a[0]); o[1] = f2bf(a[1]); o[2] = f2bf(a[2]); o[3] = f2bf(a[3]);
  o[4] = f2bf(b[0]); o[5] = f2bf(b[1]); o[6] = f2bf(b[2]); o[7] = f2bf(b[3]);
  return o;
}

#define MFMA(a, b, c) __builtin_amdgcn_mfma_f32_16x16x32_bf16((a), (b), (c), 0, 0, 0)

static __device__ __forceinline__ void gload16(const void* g, void* l) {
  __builtin_amdgcn_global_load_lds(
      (const __attribute__((address_space(1))) u32*)(g),
      (__attribute__((address_space(3))) u32*)(l), 16, 0, 0);
}

#define LDS_STRIDE 272

// Kernel 1: projections. grid = B * (N/64), block = 256.
// qb[b][n][ct] plain; kb[b][n][ct^((n&7)<<3)] (XOR-swizzled rows);
// vtb[b][ct][n0 + ((n&63)^((ct&7)<<3))] (XOR-swizzled within 64-col groups);
// xT[b][n][c] plain.
__global__ __launch_bounds__(256) void proj_kernel(
    const float* __restrict__ x, const float* __restrict__ Wq,
    const float* __restrict__ Wk, const float* __restrict__ Wv,
    short* __restrict__ qb, short* __restrict__ kb,
    short* __restrict__ vtb, short* __restrict__ xT) {
  __shared__ short xt[64 * LDS_STRIDE];
  const int b = blockIdx.x >> 6;
  const int n0 = (blockIdx.x & 63) * 64;
  const int tid = threadIdx.x;
  const int w = tid >> 6;
  const int l = tid & 63;
  const int lr = l & 15;
  const int lg = l >> 4;

  // stage x tile (C=256 x 64 n) into LDS transposed as bf16
  {
    const float* xb = x + (size_t)b * C_DIM * N_DIM + n0;
    const int n = tid & 63;
    const int cbase = tid >> 6;
#pragma unroll 4
    for (int it = 0; it < 64; ++it) {
      const int c = it * 4 + cbase;
      xt[n * LDS_STRIDE + c] = f2bf(xb[(size_t)c * N_DIM + n]);
    }
  }
  __syncthreads();

  // write xT to global (coalesced, from LDS)
  {
    const int nn = tid >> 5;
    const int cc = (tid & 31) * 8;
#pragma unroll
    for (int it = 0; it < 8; ++it) {
      const int row = it * 8 + nn;
      bf16x8 v = *reinterpret_cast<const bf16x8*>(&xt[row * LDS_STRIDE + cc]);
      *reinterpret_cast<bf16x8*>(&xT[((size_t)(b * N_DIM) + n0 + row) * C_DIM + cc]) = v;
    }
  }

  f32x4 zz; zz[0] = 0.f; zz[1] = 0.f; zz[2] = 0.f; zz[3] = 0.f;

  // q and k passes: output (n, ct). wave w owns ct range [w*64, w*64+64)
  for (int pass = 0; pass < 2; ++pass) {
    const float* W = pass ? Wk : Wq;
    short* dst = pass ? kb : qb;
    f32x4 acc[4][4];
#pragma unroll
    for (int cs = 0; cs < 4; ++cs)
#pragma unroll
      for (int ns = 0; ns < 4; ++ns) acc[cs][ns] = zz;
#pragma unroll
    for (int kk = 0; kk < 8; ++kk) {
      bf16x8 af[4], bf[4];
#pragma unroll
      for (int ns = 0; ns < 4; ++ns)
        af[ns] = *reinterpret_cast<const bf16x8*>(&xt[(ns * 16 + lr) * LDS_STRIDE + kk * 32 + lg * 8]);
#pragma unroll
      for (int cs = 0; cs < 4; ++cs)
        bf[cs] = ldW8(&W[(size_t)(w * 64 + cs * 16 + lr) * C_DIM + kk * 32 + lg * 8]);
#pragma unroll
      for (int cs = 0; cs < 4; ++cs)
#pragma unroll
        for (int ns = 0; ns < 4; ++ns) acc[cs][ns] = MFMA(af[ns], bf[cs], acc[cs][ns]);
    }
#pragma unroll
    for (int cs = 0; cs < 4; ++cs)
#pragma unroll
      for (int ns = 0; ns < 4; ++ns)
#pragma unroll
        for (int r = 0; r < 4; ++r) {
          const int n = n0 + ns * 16 + lg * 4 + r;
          const int ct = w * 64 + cs * 16 + lr;
          const int sw = pass ? ((((lg * 4 + r) & 7)) << 3) : 0;  // n&7 == (lg*4+r)&7
          dst[((size_t)(b * N_DIM) + n) * CT_DIM + (ct ^ sw)] = f2bf(acc[cs][ns][r]);
        }
  }

  // v pass: output (ct, n), swizzled within the 64-wide n group
  {
    f32x4 acc[4][4];
#pragma unroll
    for (int as = 0; as < 4; ++as)
#pragma unroll
      for (int ns = 0; ns < 4; ++ns) acc[as][ns] = zz;
#pragma unroll
    for (int kk = 0; kk < 8; ++kk) {
      bf16x8 af[4], bf[4];
#pragma unroll
      for (int as = 0; as < 4; ++as)
        af[as] = ldW8(&Wv[(size_t)(w * 64 + as * 16 + lr) * C_DIM + kk * 32 + lg * 8]);
#pragma unroll
      for (int ns = 0; ns < 4; ++ns)
        bf[ns] = *reinterpret_cast<const bf16x8*>(&xt[(ns * 16 + lr) * LDS_STRIDE + kk * 32 + lg * 8]);
#pragma unroll
      for (int as = 0; as < 4; ++as)
#pragma unroll
        for (int ns = 0; ns < 4; ++ns) acc[as][ns] = MFMA(af[as], bf[ns], acc[as][ns]);
    }
#pragma unroll
    for (int as = 0; as < 4; ++as)
#pragma unroll
      for (int ns = 0; ns < 4; ++ns)
#pragma unroll
        for (int r = 0; r < 4; ++r) {
          const int ct = w * 64 + as * 16 + lg * 4 + r;
          const int nl = ns * 16 + lr;
          vtb[((size_t)(b * CT_DIM) + ct) * N_DIM + n0 + (nl ^ ((ct & 7) << 3))] = f2bf(acc[as][ns][r]);
        }
  }
}

// Kernel 2: flash attention partials. grid = B * (N/128) * SPLIT, block = 256 (4 waves).
// Block handles 128 q rows (wave w owns 32), iterates 64-key tiles staged in LDS.
__global__ __launch_bounds__(256, 2) void attn_kernel(
    const short* __restrict__ qb, const short* __restrict__ kb,
    const short* __restrict__ vtb, short* __restrict__ Opart,
    float* __restrict__ mpart, float* __restrict__ lpart) {
  __shared__ short klds[64 * 256];   // K tile, rows XOR-swizzled; first 16KB reused for P
  __shared__ short vlds[256 * 64];   // V^T tile, rows XOR-swizzled

  const int bid = blockIdx.x;
  const int qt = bid & 31;
  const int s = (bid >> 5) & (SPLIT - 1);
  const int b = bid >> 7;
  const int tid = threadIdx.x;
  const int w = tid >> 6;
  const int l = tid & 63;
  const int lr = l & 15;
  const int lg = l >> 4;
  const int lr7 = lr & 7;
  const int nbase = qt * 128 + w * 32;

  // Q fragments for 2 M-tiles (32 rows) live in registers the whole kernel
  bf16x8 qf[2][8];
#pragma unroll
  for (int m = 0; m < 2; ++m) {
    const short* qrow = qb + ((size_t)(b * N_DIM) + nbase + m * 16 + lr) * CT_DIM + lg * 8;
#pragma unroll
    for (int kk = 0; kk < 8; ++kk)
      qf[m][kk] = *reinterpret_cast<const bf16x8*>(qrow + kk * 32);
  }

  f32x4 zz; zz[0] = 0.f; zz[1] = 0.f; zz[2] = 0.f; zz[3] = 0.f;
  f32x4 o[2][16];
#pragma unroll
  for (int m = 0; m < 2; ++m)
#pragma unroll
    for (int cs = 0; cs < 16; ++cs) o[m][cs] = zz;
  float m_r[2][4], l_r[2][4];
#pragma unroll
  for (int m = 0; m < 2; ++m)
#pragma unroll
    for (int r = 0; r < 4; ++r) { m_r[m][r] = -1e30f; l_r[m][r] = 0.f; }

  const char* kgbase = (const char*)(kb + ((size_t)b * N_DIM) * CT_DIM);
  const char* vgbase = (const char*)(vtb + ((size_t)b * CT_DIM) * N_DIM);
  short* pl = klds + w * 2048;  // per-wave P region [2][16][64], reuses K-tile LDS

  const int m_begin = s * (N_DIM / SPLIT);
  const int m_end = m_begin + (N_DIM / SPLIT);

  for (int m0 = m_begin; m0 < m_end; m0 += 64) {
    // ---- stage K tile (32KB) and V tile (32KB) ----
    {
      const char* ks = kgbase + (size_t)m0 * 512;  // 64 rows x 512B, contiguous
#pragma unroll
      for (int i = 0; i < 8; ++i)
        gload16(ks + w * 8192 + i * 1024 + l * 16, (char*)klds + w * 8192 + i * 1024);
#pragma unroll
      for (int i = 0; i < 8; ++i) {
        const int row = w * 64 + i * 8 + (l >> 3);      // ct row
        const int colb = (l & 7) * 16;                  // byte offset within 128B row
        gload16(vgbase + ((size_t)row * N_DIM + m0) * 2 + colb,
                (char*)vlds + w * 8192 + i * 1024);
      }
    }
    __syncthreads();

    // ---- S = Q K^T (2 M-tiles x 64 keys), K fragments reused across M ----
    f32x4 sacc[2][4];
#pragma unroll
    for (int m = 0; m < 2; ++m)
#pragma unroll
      for (int mt = 0; mt < 4; ++mt) sacc[m][mt] = zz;
#pragma unroll
    for (int kk = 0; kk < 8; ++kk) {
      const int kcol = kk * 32 + lg * 8;
#pragma unroll
      for (int mt = 0; mt < 4; ++mt) {
        bf16x8 kf = *reinterpret_cast<const bf16x8*>(
            &klds[(mt * 16 + lr) * 256 + (kcol ^ (lr7 << 3))]);
        sacc[0][mt] = MFMA(qf[0][kk], kf, sacc[0][mt]);
        sacc[1][mt] = MFMA(qf[1][kk], kf, sacc[1][mt]);
      }
    }

    // ---- online softmax (rows = lg*4+r, cols = mt*16+lr), exp in place ----
    float corr[2][4];
#pragma unroll
    for (int m = 0; m < 2; ++m) {
      float rmax[4];
#pragma unroll
      for (int r = 0; r < 4; ++r) {
        float a = fmaxf(sacc[m][0][r], sacc[m][1][r]);
        float c = fmaxf(sacc[m][2][r], sacc[m][3][r]);
        rmax[r] = fmaxf(a, c) * 0.0625f;
      }
#pragma unroll
      for (int d = 1; d < 16; d <<= 1)
#pragma unroll
        for (int r = 0; r < 4; ++r) rmax[r] = fmaxf(rmax[r], __shfl_xor(rmax[r], d));
      float rsum[4];
#pragma unroll
      for (int r = 0; r < 4; ++r) {
        const float mnew = fmaxf(m_r[m][r], rmax[r]);
        corr[m][r] = __expf(m_r[m][r] - mnew);
        m_r[m][r] = mnew;
        rsum[r] = 0.f;
      }
#pragma unroll
      for (int mt = 0; mt < 4; ++mt)
#pragma unroll
        for (int r = 0; r < 4; ++r) {
          const float p = __expf(sacc[m][mt][r] * 0.0625f - m_r[m][r]);
          sacc[m][mt][r] = p;
          rsum[r] += p;
        }
#pragma unroll
      for (int d = 1; d < 16; d <<= 1)
#pragma unroll
        for (int r = 0; r < 4; ++r) rsum[r] += __shfl_xor(rsum[r], d);
#pragma unroll
      for (int r = 0; r < 4; ++r) l_r[m][r] = l_r[m][r] * corr[m][r] + rsum[r];
    }

    // rescale O
#pragma unroll
    for (int m = 0; m < 2; ++m)
#pragma unroll
      for (int cs = 0; cs < 16; ++cs)
#pragma unroll
        for (int r = 0; r < 4; ++r) o[m][cs][r] *= corr[m][r];

    __syncthreads();  // all waves done reading K tile before P overwrites it

    // ---- P -> LDS (per-wave region inside klds), XOR-swizzled ----
#pragma unroll
    for (int m = 0; m < 2; ++m)
#pragma unroll
      for (int mt = 0; mt < 4; ++mt)
#pragma unroll
        for (int r = 0; r < 4; ++r) {
          const int prow = lg * 4 + r;
          pl[m * 1024 + prow * 64 + ((mt * 16 + lr) ^ ((prow & 7) << 3))] =
              f2bf(sacc[m][mt][r]);
        }

    // ---- O += P V ----
#pragma unroll
    for (int kk2 = 0; kk2 < 2; ++kk2) {
      const int pcol = (kk2 * 32 + lg * 8) ^ (lr7 << 3);
      bf16x8 pa0 = *reinterpret_cast<const bf16x8*>(&pl[lr * 64 + pcol]);
      bf16x8 pa1 = *reinterpret_cast<const bf16x8*>(&pl[1024 + lr * 64 + pcol]);
#pragma unroll
      for (int cs = 0; cs < 16; ++cs) {
        bf16x8 vf = *reinterpret_cast<const bf16x8*>(
            &vlds[(cs * 16 + lr) * 64 + ((kk2 * 32 + lg * 8) ^ (lr7 << 3))]);
        o[0][cs] = MFMA(pa0, vf, o[0][cs]);
        o[1][cs] = MFMA(pa1, vf, o[1][cs]);
      }
    }
    __syncthreads();  // done with K/V/P before next stage
  }

  // ---- write partials (bf16 O) ----
  short* obase = Opart + (size_t)(s * B_DIM + b) * N_DIM * CT_DIM;
#pragma unroll
  for (int m = 0; m < 2; ++m)
#pragma unroll
    for (int cs = 0; cs < 16; ++cs)
#pragma unroll
      for (int r = 0; r < 4; ++r) {
        const int n = nbase + m * 16 + lg * 4 + r;
        obase[(size_t)n * CT_DIM + cs * 16 + lr] = f2bf(o[m][cs][r]);
      }
  if (lr == 0) {
#pragma unroll
    for (int m = 0; m < 2; ++m)
#pragma unroll
      for (int r = 0; r < 4; ++r) {
        const int n = nbase + m * 16 + lg * 4 + r;
        mpart[(size_t)(s * B_DIM + b) * N_DIM + n] = m_r[m][r];
        lpart[(size_t)(s * B_DIM + b) * N_DIM + n] = l_r[m][r];
      }
  }
}

// Kernel 3: combine SPLIT partials -> ctxT bf16 (B, N, CT). grid = B*N, block = 256.
__global__ __launch_bounds__(256) void combine_kernel(
    const short* __restrict__ Opart, const float* __restrict__ mpart,
    const float* __restrict__ lpart, short* __restrict__ ctxT) {
  const int b = blockIdx.x >> 12;
  const int n = blockIdx.x & (N_DIM - 1);
  const int ct = threadIdx.x;
  const size_t row = (size_t)b * N_DIM + n;
  const size_t sstride = (size_t)B_DIM * N_DIM;
  float mv[SPLIT], lv[SPLIT];
  float mm = -1e30f;
#pragma unroll
  for (int s2 = 0; s2 < SPLIT; ++s2) {
    mv[s2] = mpart[s2 * sstride + row];
    lv[s2] = lpart[s2 * sstride + row];
    mm = fmaxf(mm, mv[s2]);
  }
  float L = 0.f, val = 0.f;
#pragma unroll
  for (int s2 = 0; s2 < SPLIT; ++s2) {
    const float e = __expf(mv[s2] - mm);
    L += e * lv[s2];
    val += e * bf2f(Opart[(s2 * sstride + row) * CT_DIM + ct]);
  }
  ctxT[row * CT_DIM + ct] = f2bf(val / L);
}

// Kernel 4: out[b][o][n] = Wo[:, :256] @ ctx + Wo[:, 256:] @ x. grid = B*(N/64), block=256.
__global__ __launch_bounds__(256) void out_kernel(
    const float* __restrict__ Wo, const short* __restrict__ ctxT,
    const short* __restrict__ xT, float* __restrict__ out) {
  const int b = blockIdx.x >> 6;
  const int n0 = (blockIdx.x & 63) * 64;
  const int tid = threadIdx.x;
  const int w = tid >> 6;
  const int l = tid & 63;
  const int lr = l & 15;
  const int lg = l >> 4;

  f32x4 zz; zz[0] = 0.f; zz[1] = 0.f; zz[2] = 0.f; zz[3] = 0.f;
  f32x4 acc[4][4];  // [os][ns]; wave w owns o range [w*64, w*64+64)
#pragma unroll
  for (int os = 0; os < 4; ++os)
#pragma unroll
    for (int ns = 0; ns < 4; ++ns) acc[os][ns] = zz;

#pragma unroll 4
  for (int kk = 0; kk < 16; ++kk) {
    const short* src = (kk < 8) ? ctxT : xT;
    const int c = (kk & 7) * 32 + lg * 8;
    bf16x8 bf[4], af[4];
#pragma unroll
    for (int ns = 0; ns < 4; ++ns)
      bf[ns] = *reinterpret_cast<const bf16x8*>(&src[((size_t)(b * N_DIM) + n0 + ns * 16 + lr) * 256 + c]);
#pragma unroll
    for (int os = 0; os < 4; ++os)
      af[os] = ldW8(&Wo[(size_t)(w * 64 + os * 16 + lr) * 512 + kk * 32 + lg * 8]);
#pragma unroll
    for (int os = 0; os < 4; ++os)
#pragma unroll
      for (int ns = 0; ns < 4; ++ns) acc[os][ns] = MFMA(af[os], bf[ns], acc[os][ns]);
  }

#pragma unroll
  for (int os = 0; os < 4; ++os)
#pragma unroll
    for (int ns = 0; ns < 4; ++ns)
#pragma unroll
      for (int r = 0; r < 4; ++r) {
        const int oo = w * 64 + os * 16 + lg * 4 + r;
        const int n = n0 + ns * 16 + lr;
        out[((size_t)(b * C_DIM) + oo) * N_DIM + n] = acc[os][ns][r];
      }
}

extern "C" void kernel_launch(void* const* d_in, const int* in_sizes, int n_in,
                              void* d_out, int out_size, void* d_ws, size_t ws_size,
                              hipStream_t stream) {
  const float* x = (const float*)d_in[0];
  const float* Wq = (const float*)d_in[1];
  const float* Wk = (const float*)d_in[2];
  const float* Wv = (const float*)d_in[3];
  const float* Wo = (const float*)d_in[4];
  float* out = (float*)d_out;

  char* ws = (char*)d_ws;
  const size_t SZ_BNCT = (size_t)B_DIM * N_DIM * CT_DIM * sizeof(short);  // 8 MB
  short* qb   = (short*)(ws);
  short* kb   = (short*)(ws + SZ_BNCT);
  short* vtb  = (short*)(ws + 2 * SZ_BNCT);
  short* xT   = (short*)(ws + 3 * SZ_BNCT);
  short* ctxT = (short*)(ws + 4 * SZ_BNCT);
  short* Opart = (short*)(ws + 5 * SZ_BNCT);  // SPLIT * B * N * CT bf16 = 32 MB
  float* mpart = (float*)(ws + 5 * SZ_BNCT + (size_t)SPLIT * B_DIM * N_DIM * CT_DIM * sizeof(short));
  float* lpart = mpart + (size_t)SPLIT * B_DIM * N_DIM;

  proj_kernel<<<B_DIM * (N_DIM / 64), 256, 0, stream>>>(x, Wq, Wk, Wv, qb, kb, vtb, xT);
  attn_kernel<<<B_DIM * (N_DIM / 128) * SPLIT, 256, 0, stream>>>(qb, kb, vtb, Opart, mpart, lpart);
  combine_kernel<<<B_DIM * N_DIM, 256, 0, stream>>>(Opart, mpart, lpart, ctxT);
  out_kernel<<<B_DIM * (N_DIM / 64), 256, 0, stream>>>(Wo, ctxT, xT, out);
}

// Round 3
// 273.568 us; speedup vs baseline: 2.2954x; 1.1102x over previous
//
#include <hip/hip_runtime.h>

#define B_DIM 4
#define C_DIM 256
#define N_DIM 4096
#define CT_DIM 256
#define SPLIT 4
#define KVBLK 32

typedef float f32x4 __attribute__((ext_vector_type(4)));
typedef short bf16x8 __attribute__((ext_vector_type(8)));
typedef short bf16x4 __attribute__((ext_vector_type(4)));
typedef unsigned int u32;

static __device__ __forceinline__ short f2bf(float f) {
  u32 u = __builtin_bit_cast(u32, f);
  u += 0x7fffu + ((u >> 16) & 1u);
  return (short)(u >> 16);
}
static __device__ __forceinline__ float bf2f(short s) {
  u32 u = ((u32)(unsigned short)s) << 16;
  return __builtin_bit_cast(float, u);
}

static __device__ __forceinline__ bf16x8 ldW8(const float* __restrict__ p) {
  f32x4 a = *reinterpret_cast<const f32x4*>(p);
  f32x4 b = *reinterpret_cast<const f32x4*>(p + 4);
  bf16x8 o;
  o[0] = f2bf(a[0]); o[1] = f2bf(a[1]); o[2] = f2bf(a[2]); o[3] = f2bf(a[3]);
  o[4] = f2bf(b[0]); o[5] = f2bf(b[1]); o[6] = f2bf(b[2]); o[7] = f2bf(b[3]);
  return o;
}

#define MFMA(a, b, c) __builtin_amdgcn_mfma_f32_16x16x32_bf16((a), (b), (c), 0, 0, 0)

static __device__ __forceinline__ void gload16(const void* g, void* l) {
  __builtin_amdgcn_global_load_lds(
      (const __attribute__((address_space(1))) u32*)(g),
      (__attribute__((address_space(3))) u32*)(l), 16, 0, 0);
}

#define LDS_STRIDE 272

// Kernel 1: projections. grid = B * (N/64), block = 256.
// qb[b][n][ct] plain; kb[b][n][ct ^ ((n&7)<<3)];
// vtb[b][ct][(n&~31) + ((n&31) ^ (((ct>>1)&3)<<3))]  (swizzle within 32-n groups);
// xT[b][n][c] plain.
__global__ __launch_bounds__(256) void proj_kernel(
    const float* __restrict__ x, const float* __restrict__ Wq,
    const float* __restrict__ Wk, const float* __restrict__ Wv,
    short* __restrict__ qb, short* __restrict__ kb,
    short* __restrict__ vtb, short* __restrict__ xT) {
  __shared__ short xt[64 * LDS_STRIDE];
  const int b = blockIdx.x >> 6;
  const int n0 = (blockIdx.x & 63) * 64;
  const int tid = threadIdx.x;
  const int w = tid >> 6;
  const int l = tid & 63;
  const int lr = l & 15;
  const int lg = l >> 4;

  // stage x tile (C=256 x 64 n) into LDS transposed as bf16
  {
    const float* xb = x + (size_t)b * C_DIM * N_DIM + n0;
    const int n = tid & 63;
    const int cbase = tid >> 6;
#pragma unroll 4
    for (int it = 0; it < 64; ++it) {
      const int c = it * 4 + cbase;
      xt[n * LDS_STRIDE + c] = f2bf(xb[(size_t)c * N_DIM + n]);
    }
  }
  __syncthreads();

  // write xT to global (coalesced, from LDS)
  {
    const int nn = tid >> 5;
    const int cc = (tid & 31) * 8;
#pragma unroll
    for (int it = 0; it < 8; ++it) {
      const int row = it * 8 + nn;
      bf16x8 v = *reinterpret_cast<const bf16x8*>(&xt[row * LDS_STRIDE + cc]);
      *reinterpret_cast<bf16x8*>(&xT[((size_t)(b * N_DIM) + n0 + row) * C_DIM + cc]) = v;
    }
  }

  f32x4 zz; zz[0] = 0.f; zz[1] = 0.f; zz[2] = 0.f; zz[3] = 0.f;

  // q and k passes: output (n, ct). wave w owns ct range [w*64, w*64+64)
  for (int pass = 0; pass < 2; ++pass) {
    const float* W = pass ? Wk : Wq;
    short* dst = pass ? kb : qb;
    f32x4 acc[4][4];
#pragma unroll
    for (int cs = 0; cs < 4; ++cs)
#pragma unroll
      for (int ns = 0; ns < 4; ++ns) acc[cs][ns] = zz;
#pragma unroll
    for (int kk = 0; kk < 8; ++kk) {
      bf16x8 af[4], bf[4];
#pragma unroll
      for (int ns = 0; ns < 4; ++ns)
        af[ns] = *reinterpret_cast<const bf16x8*>(&xt[(ns * 16 + lr) * LDS_STRIDE + kk * 32 + lg * 8]);
#pragma unroll
      for (int cs = 0; cs < 4; ++cs)
        bf[cs] = ldW8(&W[(size_t)(w * 64 + cs * 16 + lr) * C_DIM + kk * 32 + lg * 8]);
#pragma unroll
      for (int cs = 0; cs < 4; ++cs)
#pragma unroll
        for (int ns = 0; ns < 4; ++ns) acc[cs][ns] = MFMA(af[ns], bf[cs], acc[cs][ns]);
    }
#pragma unroll
    for (int cs = 0; cs < 4; ++cs)
#pragma unroll
      for (int ns = 0; ns < 4; ++ns)
#pragma unroll
        for (int r = 0; r < 4; ++r) {
          const int n = n0 + ns * 16 + lg * 4 + r;
          const int ct = w * 64 + cs * 16 + lr;
          const int sw = pass ? ((((lg * 4 + r) & 7)) << 3) : 0;  // n&7 == (lg*4+r)&7
          dst[((size_t)(b * N_DIM) + n) * CT_DIM + (ct ^ sw)] = f2bf(acc[cs][ns][r]);
        }
  }

  // v pass: output (ct, n), swizzled within 32-wide n groups
  {
    f32x4 acc[4][4];
#pragma unroll
    for (int as = 0; as < 4; ++as)
#pragma unroll
      for (int ns = 0; ns < 4; ++ns) acc[as][ns] = zz;
#pragma unroll
    for (int kk = 0; kk < 8; ++kk) {
      bf16x8 af[4], bf[4];
#pragma unroll
      for (int as = 0; as < 4; ++as)
        af[as] = ldW8(&Wv[(size_t)(w * 64 + as * 16 + lr) * C_DIM + kk * 32 + lg * 8]);
#pragma unroll
      for (int ns = 0; ns < 4; ++ns)
        bf[ns] = *reinterpret_cast<const bf16x8*>(&xt[(ns * 16 + lr) * LDS_STRIDE + kk * 32 + lg * 8]);
#pragma unroll
      for (int as = 0; as < 4; ++as)
#pragma unroll
        for (int ns = 0; ns < 4; ++ns) acc[as][ns] = MFMA(af[as], bf[ns], acc[as][ns]);
    }
#pragma unroll
    for (int as = 0; as < 4; ++as)
#pragma unroll
      for (int ns = 0; ns < 4; ++ns)
#pragma unroll
        for (int r = 0; r < 4; ++r) {
          const int ct = w * 64 + as * 16 + lg * 4 + r;
          const int nl = ns * 16 + lr;
          const int nsw = (nl & 32) | ((nl & 31) ^ (((ct >> 1) & 3) << 3));
          vtb[((size_t)(b * CT_DIM) + ct) * N_DIM + n0 + nsw] = f2bf(acc[as][ns][r]);
        }
  }
}

// Kernel 2: flash attention partials. grid = 512, block = 256 (4 waves).
// XCD-pinned decode: all 32 qt-blocks of one (b,s) pair land on one XCD.
// Double-buffered 32-key tiles, counted vmcnt, raw barriers.
__global__ __launch_bounds__(256, 2) void attn_kernel(
    const short* __restrict__ qb, const short* __restrict__ kb,
    const short* __restrict__ vtb, short* __restrict__ Opart,
    float* __restrict__ mpart, float* __restrict__ lpart) {
  __shared__ short klds[2][KVBLK * 256];   // 2 x 16 KB
  __shared__ short vlds[2][256 * KVBLK];   // 2 x 16 KB
  __shared__ short plds[4][2 * 16 * 32];   // 8 KB, per-wave private

  const int bid = blockIdx.x;
  const int xcd = bid & 7;
  const int idx = bid >> 3;
  const int pair = idx >> 5;
  const int qt = idx & 31;
  const int bs = pair * 8 + xcd;  // 0..15
  const int b = bs >> 2;
  const int s = bs & 3;

  const int tid = threadIdx.x;
  const int w = tid >> 6;
  const int l = tid & 63;
  const int lr = l & 15;
  const int lg = l >> 4;
  const int nbase = qt * 128 + w * 32;

  const char* kgbase = (const char*)(kb + ((size_t)b * N_DIM) * CT_DIM);
  const char* vgbase = (const char*)(vtb + ((size_t)b * CT_DIM) * N_DIM);
  const int m_begin = s * (N_DIM / SPLIT);
  const int NT = (N_DIM / SPLIT) / KVBLK;  // 32

  // Q fragments (32 rows per wave) in registers for the whole kernel
  bf16x8 qf[2][8];
#pragma unroll
  for (int m = 0; m < 2; ++m) {
    const short* qrow = qb + ((size_t)(b * N_DIM) + nbase + m * 16 + lr) * CT_DIM + lg * 8;
#pragma unroll
    for (int kk = 0; kk < 8; ++kk)
      qf[m][kk] = *reinterpret_cast<const bf16x8*>(qrow + kk * 32);
  }

  f32x4 zz; zz[0] = 0.f; zz[1] = 0.f; zz[2] = 0.f; zz[3] = 0.f;
  f32x4 o[2][16];
#pragma unroll
  for (int m = 0; m < 2; ++m)
#pragma unroll
    for (int cs = 0; cs < 16; ++cs) o[m][cs] = zz;
  float m_r[2][4], l_r[2][4];
#pragma unroll
  for (int m = 0; m < 2; ++m)
#pragma unroll
    for (int r = 0; r < 4; ++r) { m_r[m][r] = -1e30f; l_r[m][r] = 0.f; }

  short* pl = plds[w];
  const int ksw = (lr & 7) << 3;
  const int psw = ((lr >> 1) & 3) << 3;

  // stage one 32-key tile (K 16KB + V 16KB), 8 gload16 per wave
  auto stage = [&](int m0, int buf) {
    const char* ks = kgbase + (size_t)m0 * 512;  // 32 rows x 512B contiguous
#pragma unroll
    for (int i = 0; i < 4; ++i)
      gload16(ks + w * 4096 + i * 1024 + l * 16,
              (char*)klds[buf] + w * 4096 + i * 1024);
#pragma unroll
    for (int i = 0; i < 4; ++i) {
      const int row = w * 64 + i * 16 + (l >> 2);  // ct row, 64B segment each
      gload16(vgbase + ((size_t)row * N_DIM + m0) * 2 + (l & 3) * 16,
              (char*)vlds[buf] + (w * 64 + i * 16) * 64);
    }
  };

  auto compute = [&](int cur) {
    // ---- S = Q K^T : 32 rows x 32 keys per wave ----
    f32x4 sacc[2][2];
    sacc[0][0] = zz; sacc[0][1] = zz; sacc[1][0] = zz; sacc[1][1] = zz;
#pragma unroll
    for (int kk = 0; kk < 8; ++kk) {
      const int kcol = kk * 32 + lg * 8;
#pragma unroll
      for (int mt = 0; mt < 2; ++mt) {
        bf16x8 kf = *reinterpret_cast<const bf16x8*>(
            &klds[cur][(mt * 16 + lr) * 256 + (kcol ^ ksw)]);
        sacc[0][mt] = MFMA(qf[0][kk], kf, sacc[0][mt]);
        sacc[1][mt] = MFMA(qf[1][kk], kf, sacc[1][mt]);
      }
    }

    // ---- online softmax ----
    float corr[2][4];
#pragma unroll
    for (int m = 0; m < 2; ++m) {
      float rmax[4];
#pragma unroll
      for (int r = 0; r < 4; ++r)
        rmax[r] = fmaxf(sacc[m][0][r], sacc[m][1][r]) * 0.0625f;
#pragma unroll
      for (int d = 1; d < 16; d <<= 1)
#pragma unroll
        for (int r = 0; r < 4; ++r) rmax[r] = fmaxf(rmax[r], __shfl_xor(rmax[r], d));
      float rsum[4];
#pragma unroll
      for (int r = 0; r < 4; ++r) {
        const float mnew = fmaxf(m_r[m][r], rmax[r]);
        corr[m][r] = __expf(m_r[m][r] - mnew);
        m_r[m][r] = mnew;
        rsum[r] = 0.f;
      }
#pragma unroll
      for (int mt = 0; mt < 2; ++mt)
#pragma unroll
        for (int r = 0; r < 4; ++r) {
          const float p = __expf(sacc[m][mt][r] * 0.0625f - m_r[m][r]);
          sacc[m][mt][r] = p;
          rsum[r] += p;
        }
#pragma unroll
      for (int d = 1; d < 16; d <<= 1)
#pragma unroll
        for (int r = 0; r < 4; ++r) rsum[r] += __shfl_xor(rsum[r], d);
#pragma unroll
      for (int r = 0; r < 4; ++r) l_r[m][r] = l_r[m][r] * corr[m][r] + rsum[r];
    }

    // rescale O
#pragma unroll
    for (int m = 0; m < 2; ++m)
#pragma unroll
      for (int cs = 0; cs < 16; ++cs)
#pragma unroll
        for (int r = 0; r < 4; ++r) o[m][cs][r] *= corr[m][r];

    // ---- P -> per-wave LDS, swizzled ----
#pragma unroll
    for (int m = 0; m < 2; ++m)
#pragma unroll
      for (int mt = 0; mt < 2; ++mt)
#pragma unroll
        for (int r = 0; r < 4; ++r) {
          const int prow = lg * 4 + r;
          pl[m * 512 + prow * 32 + ((mt * 16 + lr) ^ (((prow >> 1) & 3) << 3))] =
              f2bf(sacc[m][mt][r]);
        }

    // ---- O += P V ----
    bf16x8 pa0 = *reinterpret_cast<const bf16x8*>(&pl[lr * 32 + ((lg * 8) ^ psw)]);
    bf16x8 pa1 = *reinterpret_cast<const bf16x8*>(&pl[512 + lr * 32 + ((lg * 8) ^ psw)]);
#pragma unroll
    for (int cs = 0; cs < 16; ++cs) {
      bf16x8 vf = *reinterpret_cast<const bf16x8*>(
          &vlds[cur][(cs * 16 + lr) * 32 + ((lg * 8) ^ psw)]);
      o[0][cs] = MFMA(pa0, vf, o[0][cs]);
      o[1][cs] = MFMA(pa1, vf, o[1][cs]);
    }
  };

  // ---- pipelined main loop ----
  stage(m_begin, 0);
  int cur = 0;
#pragma unroll 1
  for (int t = 0; t < NT - 1; ++t) {
    stage(m_begin + (t + 1) * KVBLK, cur ^ 1);
    asm volatile("s_waitcnt vmcnt(8)" ::: "memory");
    __builtin_amdgcn_s_barrier();           // tile t fully in LDS for all waves
    __builtin_amdgcn_sched_barrier(0);
    compute(cur);
    __builtin_amdgcn_sched_barrier(0);
    __builtin_amdgcn_s_barrier();           // all waves done with buf[cur]
    cur ^= 1;
  }
  asm volatile("s_waitcnt vmcnt(0)" ::: "memory");
  __builtin_amdgcn_s_barrier();
  __builtin_amdgcn_sched_barrier(0);
  compute(cur);

  // ---- write partials: packed [slot][b][n/4][ct][4] bf16, coalesced 8B/lane ----
  short* ob = Opart + (size_t)(s * B_DIM + b) * (N_DIM / 4) * CT_DIM * 4;
#pragma unroll
  for (int m = 0; m < 2; ++m)
#pragma unroll
    for (int cs = 0; cs < 16; ++cs) {
      bf16x4 pk;
      pk[0] = f2bf(o[m][cs][0]); pk[1] = f2bf(o[m][cs][1]);
      pk[2] = f2bf(o[m][cs][2]); pk[3] = f2bf(o[m][cs][3]);
      const int row4 = (nbase >> 2) + m * 4 + lg;
      *reinterpret_cast<bf16x4*>(&ob[((size_t)row4 * CT_DIM + cs * 16 + lr) * 4]) = pk;
    }
  if (lr == 0) {
#pragma unroll
    for (int m = 0; m < 2; ++m)
#pragma unroll
      for (int r = 0; r < 4; ++r) {
        const int n = nbase + m * 16 + lg * 4 + r;
        mpart[(size_t)(s * B_DIM + b) * N_DIM + n] = m_r[m][r];
        lpart[(size_t)(s * B_DIM + b) * N_DIM + n] = l_r[m][r];
      }
  }
}

// Kernel 3: combine SPLIT partials -> ctxT bf16 (B, N, CT). grid = B*N, block = 256.
__global__ __launch_bounds__(256) void combine_kernel(
    const short* __restrict__ Opart, const float* __restrict__ mpart,
    const float* __restrict__ lpart, short* __restrict__ ctxT) {
  const int b = blockIdx.x >> 12;
  const int n = blockIdx.x & (N_DIM - 1);
  const int ct = threadIdx.x;
  const size_t row = (size_t)b * N_DIM + n;
  const size_t sstride = (size_t)B_DIM * N_DIM;
  float mv[SPLIT], lv[SPLIT];
  float mm = -1e30f;
#pragma unroll
  for (int s2 = 0; s2 < SPLIT; ++s2) {
    mv[s2] = mpart[s2 * sstride + row];
    lv[s2] = lpart[s2 * sstride + row];
    mm = fmaxf(mm, mv[s2]);
  }
  float L = 0.f, val = 0.f;
#pragma unroll
  for (int s2 = 0; s2 < SPLIT; ++s2) {
    const float e = __expf(mv[s2] - mm);
    L += e * lv[s2];
    const size_t idx =
        (((size_t)(s2 * B_DIM + b) * (N_DIM / 4) + (n >> 2)) * CT_DIM + ct) * 4 + (n & 3);
    val += e * bf2f(Opart[idx]);
  }
  ctxT[row * CT_DIM + ct] = f2bf(val / L);
}

// Kernel 4: out[b][o][n] = Wo[:, :256] @ ctx + Wo[:, 256:] @ x. grid = B*(N/64), block=256.
__global__ __launch_bounds__(256) void out_kernel(
    const float* __restrict__ Wo, const short* __restrict__ ctxT,
    const short* __restrict__ xT, float* __restrict__ out) {
  const int b = blockIdx.x >> 6;
  const int n0 = (blockIdx.x & 63) * 64;
  const int tid = threadIdx.x;
  const int w = tid >> 6;
  const int l = tid & 63;
  const int lr = l & 15;
  const int lg = l >> 4;

  f32x4 zz; zz[0] = 0.f; zz[1] = 0.f; zz[2] = 0.f; zz[3] = 0.f;
  f32x4 acc[4][4];  // [os][ns]; wave w owns o range [w*64, w*64+64)
#pragma unroll
  for (int os = 0; os < 4; ++os)
#pragma unroll
    for (int ns = 0; ns < 4; ++ns) acc[os][ns] = zz;

#pragma unroll 4
  for (int kk = 0; kk < 16; ++kk) {
    const short* src = (kk < 8) ? ctxT : xT;
    const int c = (kk & 7) * 32 + lg * 8;
    bf16x8 bf[4], af[4];
#pragma unroll
    for (int ns = 0; ns < 4; ++ns)
      bf[ns] = *reinterpret_cast<const bf16x8*>(&src[((size_t)(b * N_DIM) + n0 + ns * 16 + lr) * 256 + c]);
#pragma unroll
    for (int os = 0; os < 4; ++os)
      af[os] = ldW8(&Wo[(size_t)(w * 64 + os * 16 + lr) * 512 + kk * 32 + lg * 8]);
#pragma unroll
    for (int os = 0; os < 4; ++os)
#pragma unroll
      for (int ns = 0; ns < 4; ++ns) acc[os][ns] = MFMA(af[os], bf[ns], acc[os][ns]);
  }

#pragma unroll
  for (int os = 0; os < 4; ++os)
#pragma unroll
    for (int ns = 0; ns < 4; ++ns)
#pragma unroll
      for (int r = 0; r < 4; ++r) {
        const int oo = w * 64 + os * 16 + lg * 4 + r;
        const int n = n0 + ns * 16 + lr;
        out[((size_t)(b * C_DIM) + oo) * N_DIM + n] = acc[os][ns][r];
      }
}

extern "C" void kernel_launch(void* const* d_in, const int* in_sizes, int n_in,
                              void* d_out, int out_size, void* d_ws, size_t ws_size,
                              hipStream_t stream) {
  const float* x = (const float*)d_in[0];
  const float* Wq = (const float*)d_in[1];
  const float* Wk = (const float*)d_in[2];
  const float* Wv = (const float*)d_in[3];
  const float* Wo = (const float*)d_in[4];
  float* out = (float*)d_out;

  char* ws = (char*)d_ws;
  const size_t SZ_BNCT = (size_t)B_DIM * N_DIM * CT_DIM * sizeof(short);  // 8 MB
  short* qb   = (short*)(ws);
  short* kb   = (short*)(ws + SZ_BNCT);
  short* vtb  = (short*)(ws + 2 * SZ_BNCT);
  short* xT   = (short*)(ws + 3 * SZ_BNCT);
  short* ctxT = (short*)(ws + 4 * SZ_BNCT);
  short* Opart = (short*)(ws + 5 * SZ_BNCT);  // SPLIT * B * N * CT bf16 = 32 MB
  float* mpart = (float*)(ws + 5 * SZ_BNCT + (size_t)SPLIT * B_DIM * N_DIM * CT_DIM * sizeof(short));
  float* lpart = mpart + (size_t)SPLIT * B_DIM * N_DIM;

  proj_kernel<<<B_DIM * (N_DIM / 64), 256, 0, stream>>>(x, Wq, Wk, Wv, qb, kb, vtb, xT);
  attn_kernel<<<B_DIM * (N_DIM / 128) * SPLIT, 256, 0, stream>>>(qb, kb, vtb, Opart, mpart, lpart);
  combine_kernel<<<B_DIM * N_DIM, 256, 0, stream>>>(Opart, mpart, lpart, ctxT);
  out_kernel<<<B_DIM * (N_DIM / 64), 256, 0, stream>>>(Wo, ctxT, xT, out);
}

// Round 4
// 256.023 us; speedup vs baseline: 2.4527x; 1.0685x over previous
//
#include <hip/hip_runtime.h>

#define B_DIM 4
#define C_DIM 256
#define N_DIM 4096
#define CT_DIM 256
#define SPLIT 4
#define KVBLK 32

typedef float f32x4 __attribute__((ext_vector_type(4)));
typedef short bf16x8 __attribute__((ext_vector_type(8)));
typedef short bf16x4 __attribute__((ext_vector_type(4)));
typedef unsigned int u32;

static __device__ __forceinline__ short f2bf(float f) {
  u32 u = __builtin_bit_cast(u32, f);
  u += 0x7fffu + ((u >> 16) & 1u);
  return (short)(u >> 16);
}
static __device__ __forceinline__ float bf2f(short s) {
  u32 u = ((u32)(unsigned short)s) << 16;
  return __builtin_bit_cast(float, u);
}

static __device__ __forceinline__ bf16x8 ldW8(const float* __restrict__ p) {
  f32x4 a = *reinterpret_cast<const f32x4*>(p);
  f32x4 b = *reinterpret_cast<const f32x4*>(p + 4);
  bf16x8 o;
  o[0] = f2bf(a[0]); o[1] = f2bf(a[1]); o[2] = f2bf(a[2]); o[3] = f2bf(a[3]);
  o[4] = f2bf(b[0]); o[5] = f2bf(b[1]); o[6] = f2bf(b[2]); o[7] = f2bf(b[3]);
  return o;
}

#define MFMA(a, b, c) __builtin_amdgcn_mfma_f32_16x16x32_bf16((a), (b), (c), 0, 0, 0)

static __device__ __forceinline__ void gload16(const void* g, void* l) {
  __builtin_amdgcn_global_load_lds(
      (const __attribute__((address_space(1))) u32*)(g),
      (__attribute__((address_space(3))) u32*)(l), 16, 0, 0);
}

#define LDS_STRIDE 272

// Kernel 1: projections. grid = B * (N/64), block = 256.
// qb[b][n][ct] plain, PRE-SCALED by 2^-4 (softmax norm, exact in bf16);
// kb[b][n][ct ^ ((n&7)<<3)];
// vtb[b][ct][(n&~31) + ((n&31) ^ (((ct>>1)&3)<<3))];
// xT[b][n][c] plain.
__global__ __launch_bounds__(256) void proj_kernel(
    const float* __restrict__ x, const float* __restrict__ Wq,
    const float* __restrict__ Wk, const float* __restrict__ Wv,
    short* __restrict__ qb, short* __restrict__ kb,
    short* __restrict__ vtb, short* __restrict__ xT) {
  __shared__ short xt[64 * LDS_STRIDE];
  const int b = blockIdx.x >> 6;
  const int n0 = (blockIdx.x & 63) * 64;
  const int tid = threadIdx.x;
  const int w = tid >> 6;
  const int l = tid & 63;
  const int lr = l & 15;
  const int lg = l >> 4;

  // stage x tile (C=256 x 64 n) into LDS transposed as bf16
  {
    const float* xb = x + (size_t)b * C_DIM * N_DIM + n0;
    const int n = tid & 63;
    const int cbase = tid >> 6;
#pragma unroll 4
    for (int it = 0; it < 64; ++it) {
      const int c = it * 4 + cbase;
      xt[n * LDS_STRIDE + c] = f2bf(xb[(size_t)c * N_DIM + n]);
    }
  }
  __syncthreads();

  // write xT to global (coalesced, from LDS)
  {
    const int nn = tid >> 5;
    const int cc = (tid & 31) * 8;
#pragma unroll
    for (int it = 0; it < 8; ++it) {
      const int row = it * 8 + nn;
      bf16x8 v = *reinterpret_cast<const bf16x8*>(&xt[row * LDS_STRIDE + cc]);
      *reinterpret_cast<bf16x8*>(&xT[((size_t)(b * N_DIM) + n0 + row) * C_DIM + cc]) = v;
    }
  }

  f32x4 zz; zz[0] = 0.f; zz[1] = 0.f; zz[2] = 0.f; zz[3] = 0.f;

  // q and k passes: output (n, ct). wave w owns ct range [w*64, w*64+64)
  for (int pass = 0; pass < 2; ++pass) {
    const float* W = pass ? Wk : Wq;
    short* dst = pass ? kb : qb;
    const float oscale = pass ? 1.0f : 0.0625f;
    f32x4 acc[4][4];
#pragma unroll
    for (int cs = 0; cs < 4; ++cs)
#pragma unroll
      for (int ns = 0; ns < 4; ++ns) acc[cs][ns] = zz;
#pragma unroll
    for (int kk = 0; kk < 8; ++kk) {
      bf16x8 af[4], bf[4];
#pragma unroll
      for (int ns = 0; ns < 4; ++ns)
        af[ns] = *reinterpret_cast<const bf16x8*>(&xt[(ns * 16 + lr) * LDS_STRIDE + kk * 32 + lg * 8]);
#pragma unroll
      for (int cs = 0; cs < 4; ++cs)
        bf[cs] = ldW8(&W[(size_t)(w * 64 + cs * 16 + lr) * C_DIM + kk * 32 + lg * 8]);
#pragma unroll
      for (int cs = 0; cs < 4; ++cs)
#pragma unroll
        for (int ns = 0; ns < 4; ++ns) acc[cs][ns] = MFMA(af[ns], bf[cs], acc[cs][ns]);
    }
#pragma unroll
    for (int cs = 0; cs < 4; ++cs)
#pragma unroll
      for (int ns = 0; ns < 4; ++ns)
#pragma unroll
        for (int r = 0; r < 4; ++r) {
          const int n = n0 + ns * 16 + lg * 4 + r;
          const int ct = w * 64 + cs * 16 + lr;
          const int sw = pass ? ((((lg * 4 + r) & 7)) << 3) : 0;  // n&7 == (lg*4+r)&7
          dst[((size_t)(b * N_DIM) + n) * CT_DIM + (ct ^ sw)] = f2bf(acc[cs][ns][r] * oscale);
        }
  }

  // v pass: output (ct, n), swizzled within 32-wide n groups
  {
    f32x4 acc[4][4];
#pragma unroll
    for (int as = 0; as < 4; ++as)
#pragma unroll
      for (int ns = 0; ns < 4; ++ns) acc[as][ns] = zz;
#pragma unroll
    for (int kk = 0; kk < 8; ++kk) {
      bf16x8 af[4], bf[4];
#pragma unroll
      for (int as = 0; as < 4; ++as)
        af[as] = ldW8(&Wv[(size_t)(w * 64 + as * 16 + lr) * C_DIM + kk * 32 + lg * 8]);
#pragma unroll
      for (int ns = 0; ns < 4; ++ns)
        bf[ns] = *reinterpret_cast<const bf16x8*>(&xt[(ns * 16 + lr) * LDS_STRIDE + kk * 32 + lg * 8]);
#pragma unroll
      for (int as = 0; as < 4; ++as)
#pragma unroll
        for (int ns = 0; ns < 4; ++ns) acc[as][ns] = MFMA(af[as], bf[ns], acc[as][ns]);
    }
#pragma unroll
    for (int as = 0; as < 4; ++as)
#pragma unroll
      for (int ns = 0; ns < 4; ++ns)
#pragma unroll
        for (int r = 0; r < 4; ++r) {
          const int ct = w * 64 + as * 16 + lg * 4 + r;
          const int nl = ns * 16 + lr;
          const int nsw = (nl & 32) | ((nl & 31) ^ (((ct >> 1) & 3) << 3));
          vtb[((size_t)(b * CT_DIM) + ct) * N_DIM + n0 + nsw] = f2bf(acc[as][ns][r]);
        }
  }
}

// Kernel 2: flash attention partials. grid = 256, block = 512 (8 waves), 1 block/CU.
// XCD-pinned; triple-buffered 32-key K/V tiles; ONE barrier per iteration;
// counted vmcnt(4) keeps next tile in flight across the barrier.
__global__ __launch_bounds__(512, 1) void attn_kernel(
    const short* __restrict__ qb, const short* __restrict__ kb,
    const short* __restrict__ vtb, short* __restrict__ Opart,
    float* __restrict__ mpart, float* __restrict__ lpart) {
  __shared__ short klds[3][KVBLK * 256];   // 3 x 16 KB
  __shared__ short vlds[3][256 * KVBLK];   // 3 x 16 KB
  __shared__ short plds[8][2 * 16 * 32];   // 16 KB (per-wave private P)

  const int bid = blockIdx.x;
  const int xcd = bid & 7;
  const int idx = bid >> 3;          // 0..31
  const int qt = idx & 15;
  const int bs = (idx >> 4) * 8 + xcd;  // 0..15
  const int b = bs >> 2;
  const int s = bs & 3;

  const int tid = threadIdx.x;
  const int w = tid >> 6;            // 0..7
  const int l = tid & 63;
  const int lr = l & 15;
  const int lg = l >> 4;
  const int nbase = qt * 256 + w * 32;

  const char* kgbase = (const char*)(kb + ((size_t)b * N_DIM) * CT_DIM);
  const char* vgbase = (const char*)(vtb + ((size_t)b * CT_DIM) * N_DIM);
  const int m_begin = s * (N_DIM / SPLIT);
  const int NT = (N_DIM / SPLIT) / KVBLK;  // 32

  // Q fragments (32 rows per wave) in registers for the whole kernel
  bf16x8 qf[2][8];
#pragma unroll
  for (int m = 0; m < 2; ++m) {
    const short* qrow = qb + ((size_t)(b * N_DIM) + nbase + m * 16 + lr) * CT_DIM + lg * 8;
#pragma unroll
    for (int kk = 0; kk < 8; ++kk)
      qf[m][kk] = *reinterpret_cast<const bf16x8*>(qrow + kk * 32);
  }

  f32x4 zz; zz[0] = 0.f; zz[1] = 0.f; zz[2] = 0.f; zz[3] = 0.f;
  f32x4 o[2][16];
#pragma unroll
  for (int m = 0; m < 2; ++m)
#pragma unroll
    for (int cs = 0; cs < 16; ++cs) o[m][cs] = zz;
  float m_r[2][4], l_r[2][4];
#pragma unroll
  for (int m = 0; m < 2; ++m)
#pragma unroll
    for (int r = 0; r < 4; ++r) { m_r[m][r] = -1e30f; l_r[m][r] = 0.f; }

  short* pl = plds[w];
  const int ksw = (lr & 7) << 3;
  const int psw = ((lr >> 1) & 3) << 3;

  // stage one 32-key tile (K 16KB + V 16KB), 4 gload16 per wave
  auto stage = [&](int m0, int buf) {
    const char* ks = kgbase + (size_t)m0 * 512;  // 32 rows x 512B contiguous
#pragma unroll
    for (int i = 0; i < 2; ++i)
      gload16(ks + (w * 2 + i) * 1024 + l * 16,
              (char*)klds[buf] + (w * 2 + i) * 1024);
#pragma unroll
    for (int i = 0; i < 2; ++i) {
      const int row = w * 32 + i * 16 + (l >> 2);  // ct row
      gload16(vgbase + ((size_t)row * N_DIM + m0) * 2 + (l & 3) * 16,
              (char*)vlds[buf] + (w * 32 + i * 16) * 64);
    }
  };

  auto compute = [&](int cur) {
    // ---- S = Q K^T : 32 rows x 32 keys per wave (q pre-scaled by 2^-4) ----
    f32x4 sacc[2][2];
    sacc[0][0] = zz; sacc[0][1] = zz; sacc[1][0] = zz; sacc[1][1] = zz;
    __builtin_amdgcn_s_setprio(1);
#pragma unroll
    for (int kk = 0; kk < 8; ++kk) {
      const int kcol = kk * 32 + lg * 8;
#pragma unroll
      for (int mt = 0; mt < 2; ++mt) {
        bf16x8 kf = *reinterpret_cast<const bf16x8*>(
            &klds[cur][(mt * 16 + lr) * 256 + (kcol ^ ksw)]);
        sacc[0][mt] = MFMA(qf[0][kk], kf, sacc[0][mt]);
        sacc[1][mt] = MFMA(qf[1][kk], kf, sacc[1][mt]);
      }
    }
    __builtin_amdgcn_s_setprio(0);

    // ---- online softmax with exact defer-rescale ----
#pragma unroll
    for (int m = 0; m < 2; ++m) {
      float rmax[4];
#pragma unroll
      for (int r = 0; r < 4; ++r)
        rmax[r] = fmaxf(sacc[m][0][r], sacc[m][1][r]);
#pragma unroll
      for (int d = 1; d < 16; d <<= 1)
#pragma unroll
        for (int r = 0; r < 4; ++r) rmax[r] = fmaxf(rmax[r], __shfl_xor(rmax[r], d));

      bool grow = false;
#pragma unroll
      for (int r = 0; r < 4; ++r) grow = grow || (rmax[r] > m_r[m][r]);
      const bool need = __any(grow);

      float corr[4], rsum[4];
      if (need) {
#pragma unroll
        for (int r = 0; r < 4; ++r) {
          const float mnew = fmaxf(m_r[m][r], rmax[r]);
          corr[r] = __expf(m_r[m][r] - mnew);
          m_r[m][r] = mnew;
        }
      }
#pragma unroll
      for (int r = 0; r < 4; ++r) rsum[r] = 0.f;
#pragma unroll
      for (int mt = 0; mt < 2; ++mt)
#pragma unroll
        for (int r = 0; r < 4; ++r) {
          const float p = __expf(sacc[m][mt][r] - m_r[m][r]);
          sacc[m][mt][r] = p;
          rsum[r] += p;
        }
#pragma unroll
      for (int d = 1; d < 16; d <<= 1)
#pragma unroll
        for (int r = 0; r < 4; ++r) rsum[r] += __shfl_xor(rsum[r], d);
      if (need) {
#pragma unroll
        for (int r = 0; r < 4; ++r) l_r[m][r] = l_r[m][r] * corr[r] + rsum[r];
#pragma unroll
        for (int cs = 0; cs < 16; ++cs)
#pragma unroll
          for (int r = 0; r < 4; ++r) o[m][cs][r] *= corr[r];
      } else {
#pragma unroll
        for (int r = 0; r < 4; ++r) l_r[m][r] += rsum[r];
      }
    }

    // ---- P -> per-wave LDS, swizzled ----
#pragma unroll
    for (int m = 0; m < 2; ++m)
#pragma unroll
      for (int mt = 0; mt < 2; ++mt)
#pragma unroll
        for (int r = 0; r < 4; ++r) {
          const int prow = lg * 4 + r;
          pl[m * 512 + prow * 32 + ((mt * 16 + lr) ^ (((prow >> 1) & 3) << 3))] =
              f2bf(sacc[m][mt][r]);
        }

    // ---- O += P V ----
    bf16x8 pa0 = *reinterpret_cast<const bf16x8*>(&pl[lr * 32 + ((lg * 8) ^ psw)]);
    bf16x8 pa1 = *reinterpret_cast<const bf16x8*>(&pl[512 + lr * 32 + ((lg * 8) ^ psw)]);
    __builtin_amdgcn_s_setprio(1);
#pragma unroll
    for (int cs = 0; cs < 16; ++cs) {
      bf16x8 vf = *reinterpret_cast<const bf16x8*>(
          &vlds[cur][(cs * 16 + lr) * 32 + ((lg * 8) ^ psw)]);
      o[0][cs] = MFMA(pa0, vf, o[0][cs]);
      o[1][cs] = MFMA(pa1, vf, o[1][cs]);
    }
    __builtin_amdgcn_s_setprio(0);
  };

  // ---- main loop: 1 barrier per iter, triple buffer, distance-1 prefetch ----
  stage(m_begin, 0);
  int cur = 0;
#pragma unroll 1
  for (int t = 0; t < NT; ++t) {
    if (t + 1 < NT) {
      stage(m_begin + (t + 1) * KVBLK, cur == 2 ? 0 : cur + 1);
      asm volatile("s_waitcnt vmcnt(4)" ::: "memory");
    } else {
      asm volatile("s_waitcnt vmcnt(0)" ::: "memory");
    }
    __builtin_amdgcn_s_barrier();
    __builtin_amdgcn_sched_barrier(0);
    compute(cur);
    cur = (cur == 2) ? 0 : cur + 1;
  }

  // ---- write partials: packed [slot][b][n/4][ct][4] bf16, coalesced 8B/lane ----
  short* ob = Opart + (size_t)(s * B_DIM + b) * (N_DIM / 4) * CT_DIM * 4;
#pragma unroll
  for (int m = 0; m < 2; ++m)
#pragma unroll
    for (int cs = 0; cs < 16; ++cs) {
      bf16x4 pk;
      pk[0] = f2bf(o[m][cs][0]); pk[1] = f2bf(o[m][cs][1]);
      pk[2] = f2bf(o[m][cs][2]); pk[3] = f2bf(o[m][cs][3]);
      const int row4 = (nbase >> 2) + m * 4 + lg;
      *reinterpret_cast<bf16x4*>(&ob[((size_t)row4 * CT_DIM + cs * 16 + lr) * 4]) = pk;
    }
  if (lr == 0) {
#pragma unroll
    for (int m = 0; m < 2; ++m)
#pragma unroll
      for (int r = 0; r < 4; ++r) {
        const int n = nbase + m * 16 + lg * 4 + r;
        mpart[(size_t)(s * B_DIM + b) * N_DIM + n] = m_r[m][r];
        lpart[(size_t)(s * B_DIM + b) * N_DIM + n] = l_r[m][r];
      }
  }
}

// Kernel 3: combine SPLIT partials -> ctxT bf16 (B, N, CT).
// grid = B*N/4 blocks; thread ct handles 4 consecutive n (bf16x4 coalesced).
__global__ __launch_bounds__(256) void combine_kernel(
    const short* __restrict__ Opart, const float* __restrict__ mpart,
    const float* __restrict__ lpart, short* __restrict__ ctxT) {
  const int blk = blockIdx.x;
  const int b = blk >> 10;           // N/4 = 1024
  const int n4 = blk & 1023;
  const int ct = threadIdx.x;
  const size_t sstride = (size_t)B_DIM * N_DIM;

  float mm[4], L[4], val[4];
#pragma unroll
  for (int j = 0; j < 4; ++j) { mm[j] = -1e30f; L[j] = 0.f; val[j] = 0.f; }
  float mv[SPLIT][4];
#pragma unroll
  for (int s2 = 0; s2 < SPLIT; ++s2)
#pragma unroll
    for (int j = 0; j < 4; ++j) {
      mv[s2][j] = mpart[s2 * sstride + (size_t)b * N_DIM + n4 * 4 + j];
      mm[j] = fmaxf(mm[j], mv[s2][j]);
    }
#pragma unroll
  for (int s2 = 0; s2 < SPLIT; ++s2) {
    bf16x4 ov = *reinterpret_cast<const bf16x4*>(
        &Opart[(((size_t)(s2 * B_DIM + b) * (N_DIM / 4) + n4) * CT_DIM + ct) * 4]);
#pragma unroll
    for (int j = 0; j < 4; ++j) {
      const float e = __expf(mv[s2][j] - mm[j]);
      L[j] += e * lpart[s2 * sstride + (size_t)b * N_DIM + n4 * 4 + j];
      val[j] += e * bf2f(ov[j]);
    }
  }
#pragma unroll
  for (int j = 0; j < 4; ++j)
    ctxT[((size_t)b * N_DIM + n4 * 4 + j) * CT_DIM + ct] = f2bf(val[j] / L[j]);
}

// Kernel 4: out[b][o][n] = Wo[:, :256] @ ctx + Wo[:, 256:] @ x. grid = B*(N/64), block=256.
__global__ __launch_bounds__(256) void out_kernel(
    const float* __restrict__ Wo, const short* __restrict__ ctxT,
    const short* __restrict__ xT, float* __restrict__ out) {
  const int b = blockIdx.x >> 6;
  const int n0 = (blockIdx.x & 63) * 64;
  const int tid = threadIdx.x;
  const int w = tid >> 6;
  const int l = tid & 63;
  const int lr = l & 15;
  const int lg = l >> 4;

  f32x4 zz; zz[0] = 0.f; zz[1] = 0.f; zz[2] = 0.f; zz[3] = 0.f;
  f32x4 acc[4][4];  // [os][ns]; wave w owns o range [w*64, w*64+64)
#pragma unroll
  for (int os = 0; os < 4; ++os)
#pragma unroll
    for (int ns = 0; ns < 4; ++ns) acc[os][ns] = zz;

#pragma unroll 4
  for (int kk = 0; kk < 16; ++kk) {
    const short* src = (kk < 8) ? ctxT : xT;
    const int c = (kk & 7) * 32 + lg * 8;
    bf16x8 bf[4], af[4];
#pragma unroll
    for (int ns = 0; ns < 4; ++ns)
      bf[ns] = *reinterpret_cast<const bf16x8*>(&src[((size_t)(b * N_DIM) + n0 + ns * 16 + lr) * 256 + c]);
#pragma unroll
    for (int os = 0; os < 4; ++os)
      af[os] = ldW8(&Wo[(size_t)(w * 64 + os * 16 + lr) * 512 + kk * 32 + lg * 8]);
#pragma unroll
    for (int os = 0; os < 4; ++os)
#pragma unroll
      for (int ns = 0; ns < 4; ++ns) acc[os][ns] = MFMA(af[os], bf[ns], acc[os][ns]);
  }

#pragma unroll
  for (int os = 0; os < 4; ++os)
#pragma unroll
    for (int ns = 0; ns < 4; ++ns)
#pragma unroll
      for (int r = 0; r < 4; ++r) {
        const int oo = w * 64 + os * 16 + lg * 4 + r;
        const int n = n0 + ns * 16 + lr;
        out[((size_t)(b * C_DIM) + oo) * N_DIM + n] = acc[os][ns][r];
      }
}

extern "C" void kernel_launch(void* const* d_in, const int* in_sizes, int n_in,
                              void* d_out, int out_size, void* d_ws, size_t ws_size,
                              hipStream_t stream) {
  const float* x = (const float*)d_in[0];
  const float* Wq = (const float*)d_in[1];
  const float* Wk = (const float*)d_in[2];
  const float* Wv = (const float*)d_in[3];
  const float* Wo = (const float*)d_in[4];
  float* out = (float*)d_out;

  char* ws = (char*)d_ws;
  const size_t SZ_BNCT = (size_t)B_DIM * N_DIM * CT_DIM * sizeof(short);  // 8 MB
  short* qb   = (short*)(ws);
  short* kb   = (short*)(ws + SZ_BNCT);
  short* vtb  = (short*)(ws + 2 * SZ_BNCT);
  short* xT   = (short*)(ws + 3 * SZ_BNCT);
  short* ctxT = (short*)(ws + 4 * SZ_BNCT);
  short* Opart = (short*)(ws + 5 * SZ_BNCT);  // SPLIT * B * N * CT bf16 = 32 MB
  float* mpart = (float*)(ws + 5 * SZ_BNCT + (size_t)SPLIT * B_DIM * N_DIM * CT_DIM * sizeof(short));
  float* lpart = mpart + (size_t)SPLIT * B_DIM * N_DIM;

  proj_kernel<<<B_DIM * (N_DIM / 64), 256, 0, stream>>>(x, Wq, Wk, Wv, qb, kb, vtb, xT);
  attn_kernel<<<B_DIM * (N_DIM / 256) * SPLIT, 512, 0, stream>>>(qb, kb, vtb, Opart, mpart, lpart);
  combine_kernel<<<B_DIM * N_DIM / 4, 256, 0, stream>>>(Opart, mpart, lpart, ctxT);
  out_kernel<<<B_DIM * (N_DIM / 64), 256, 0, stream>>>(Wo, ctxT, xT, out);
}

// Round 5
// 162.265 us; speedup vs baseline: 3.8699x; 1.5778x over previous
//
#include <hip/hip_runtime.h>

#define B_DIM 4
#define C_DIM 256
#define N_DIM 4096
#define CT_DIM 256
#define SPLIT 4
#define KVBLK 32

typedef float f32x4 __attribute__((ext_vector_type(4)));
typedef float f32x16 __attribute__((ext_vector_type(16)));
typedef short bf16x8 __attribute__((ext_vector_type(8)));
typedef short bf16x4 __attribute__((ext_vector_type(4)));
typedef unsigned int u32;

static __device__ __forceinline__ short f2bf(float f) {
  u32 u = __builtin_bit_cast(u32, f);
  u += 0x7fffu + ((u >> 16) & 1u);
  return (short)(u >> 16);
}
static __device__ __forceinline__ float bf2f(short s) {
  u32 u = ((u32)(unsigned short)s) << 16;
  return __builtin_bit_cast(float, u);
}
static __device__ __forceinline__ u32 pack2(float a, float b) {
  return (u32)(unsigned short)f2bf(a) | ((u32)(unsigned short)f2bf(b) << 16);
}

static __device__ __forceinline__ bf16x8 ldW8(const float* __restrict__ p) {
  f32x4 a = *reinterpret_cast<const f32x4*>(p);
  f32x4 b = *reinterpret_cast<const f32x4*>(p + 4);
  bf16x8 o;
  o[0] = f2bf(a[0]); o[1] = f2bf(a[1]); o[2] = f2bf(a[2]); o[3] = f2bf(a[3]);
  o[4] = f2bf(b[0]); o[5] = f2bf(b[1]); o[6] = f2bf(b[2]); o[7] = f2bf(b[3]);
  return o;
}

#define MFMA(a, b, c) __builtin_amdgcn_mfma_f32_16x16x32_bf16((a), (b), (c), 0, 0, 0)
#define MFMA32(a, b, c) __builtin_amdgcn_mfma_f32_32x32x16_bf16((a), (b), (c), 0, 0, 0)

static __device__ __forceinline__ void gload16(const void* g, void* l) {
  __builtin_amdgcn_global_load_lds(
      (const __attribute__((address_space(1))) u32*)(g),
      (__attribute__((address_space(3))) u32*)(l), 16, 0, 0);
}

#define LDS_STRIDE 272

// Kernel 1: projections. grid = B * (N/64), block = 256.
// qb[b][n][ct] plain, PRE-SCALED by 2^-4 (softmax norm, exact in bf16);
// kb[b][n][ct ^ ((n&15)<<3)]  (16-row swizzle for the 32-row A-operand read);
// vtb[b][ct][(n&~31) + ((n&31) ^ ((ct&3)<<3))]  (swizzle within 32-n groups);
// xT[b][n][c] plain.
__global__ __launch_bounds__(256) void proj_kernel(
    const float* __restrict__ x, const float* __restrict__ Wq,
    const float* __restrict__ Wk, const float* __restrict__ Wv,
    short* __restrict__ qb, short* __restrict__ kb,
    short* __restrict__ vtb, short* __restrict__ xT) {
  __shared__ short xt[64 * LDS_STRIDE];
  const int b = blockIdx.x >> 6;
  const int n0 = (blockIdx.x & 63) * 64;
  const int tid = threadIdx.x;
  const int w = tid >> 6;
  const int l = tid & 63;
  const int lr = l & 15;
  const int lg = l >> 4;

  // stage x tile (C=256 x 64 n) into LDS transposed as bf16
  {
    const float* xb = x + (size_t)b * C_DIM * N_DIM + n0;
    const int n = tid & 63;
    const int cbase = tid >> 6;
#pragma unroll 4
    for (int it = 0; it < 64; ++it) {
      const int c = it * 4 + cbase;
      xt[n * LDS_STRIDE + c] = f2bf(xb[(size_t)c * N_DIM + n]);
    }
  }
  __syncthreads();

  // write xT to global (coalesced, from LDS)
  {
    const int nn = tid >> 5;
    const int cc = (tid & 31) * 8;
#pragma unroll
    for (int it = 0; it < 8; ++it) {
      const int row = it * 8 + nn;
      bf16x8 v = *reinterpret_cast<const bf16x8*>(&xt[row * LDS_STRIDE + cc]);
      *reinterpret_cast<bf16x8*>(&xT[((size_t)(b * N_DIM) + n0 + row) * C_DIM + cc]) = v;
    }
  }

  f32x4 zz; zz[0] = 0.f; zz[1] = 0.f; zz[2] = 0.f; zz[3] = 0.f;

  // q and k passes: output (n, ct). wave w owns ct range [w*64, w*64+64)
  for (int pass = 0; pass < 2; ++pass) {
    const float* W = pass ? Wk : Wq;
    short* dst = pass ? kb : qb;
    const float oscale = pass ? 1.0f : 0.0625f;
    f32x4 acc[4][4];
#pragma unroll
    for (int cs = 0; cs < 4; ++cs)
#pragma unroll
      for (int ns = 0; ns < 4; ++ns) acc[cs][ns] = zz;
#pragma unroll
    for (int kk = 0; kk < 8; ++kk) {
      bf16x8 af[4], bf[4];
#pragma unroll
      for (int ns = 0; ns < 4; ++ns)
        af[ns] = *reinterpret_cast<const bf16x8*>(&xt[(ns * 16 + lr) * LDS_STRIDE + kk * 32 + lg * 8]);
#pragma unroll
      for (int cs = 0; cs < 4; ++cs)
        bf[cs] = ldW8(&W[(size_t)(w * 64 + cs * 16 + lr) * C_DIM + kk * 32 + lg * 8]);
#pragma unroll
      for (int cs = 0; cs < 4; ++cs)
#pragma unroll
        for (int ns = 0; ns < 4; ++ns) acc[cs][ns] = MFMA(af[ns], bf[cs], acc[cs][ns]);
    }
#pragma unroll
    for (int cs = 0; cs < 4; ++cs)
#pragma unroll
      for (int ns = 0; ns < 4; ++ns)
#pragma unroll
        for (int r = 0; r < 4; ++r) {
          const int n = n0 + ns * 16 + lg * 4 + r;
          const int ct = w * 64 + cs * 16 + lr;
          const int sw = pass ? ((lg * 4 + r) << 3) : 0;  // n&15 == lg*4+r
          dst[((size_t)(b * N_DIM) + n) * CT_DIM + (ct ^ sw)] = f2bf(acc[cs][ns][r] * oscale);
        }
  }

  // v pass: output (ct, n), swizzled within 32-wide n groups
  {
    f32x4 acc[4][4];
#pragma unroll
    for (int as = 0; as < 4; ++as)
#pragma unroll
      for (int ns = 0; ns < 4; ++ns) acc[as][ns] = zz;
#pragma unroll
    for (int kk = 0; kk < 8; ++kk) {
      bf16x8 af[4], bf[4];
#pragma unroll
      for (int as = 0; as < 4; ++as)
        af[as] = ldW8(&Wv[(size_t)(w * 64 + as * 16 + lr) * C_DIM + kk * 32 + lg * 8]);
#pragma unroll
      for (int ns = 0; ns < 4; ++ns)
        bf[ns] = *reinterpret_cast<const bf16x8*>(&xt[(ns * 16 + lr) * LDS_STRIDE + kk * 32 + lg * 8]);
#pragma unroll
      for (int as = 0; as < 4; ++as)
#pragma unroll
        for (int ns = 0; ns < 4; ++ns) acc[as][ns] = MFMA(af[as], bf[ns], acc[as][ns]);
    }
#pragma unroll
    for (int as = 0; as < 4; ++as)
#pragma unroll
      for (int ns = 0; ns < 4; ++ns)
#pragma unroll
        for (int r = 0; r < 4; ++r) {
          const int ct = w * 64 + as * 16 + lg * 4 + r;
          const int nl = ns * 16 + lr;
          const int nsw = (nl & 32) | ((nl & 31) ^ ((ct & 3) << 3));
          vtb[((size_t)(b * CT_DIM) + ct) * N_DIM + n0 + nsw] = f2bf(acc[as][ns][r]);
        }
  }
}

// Kernel 2: flash attention, swapped-QK 32x32x16 structure.
// grid = 256 (XCD-pinned), block = 512 (8 waves). Each wave owns 32 q-rows;
// lane l&31 owns ONE q-row; softmax is in-lane + one shfl_xor(32).
__global__ __launch_bounds__(512, 1) void attn_kernel(
    const short* __restrict__ qb, const short* __restrict__ kb,
    const short* __restrict__ vtb, short* __restrict__ Opart,
    float* __restrict__ mpart, float* __restrict__ lpart) {
  __shared__ short klds[3][KVBLK * 256];   // 3 x 16 KB
  __shared__ short vlds[3][256 * KVBLK];   // 3 x 16 KB

  const int bid = blockIdx.x;
  const int xcd = bid & 7;
  const int idx = bid >> 3;          // 0..31
  const int qt = idx & 15;
  const int bs = (idx >> 4) * 8 + xcd;  // 0..15
  const int b = bs >> 2;
  const int s = bs & 3;

  const int tid = threadIdx.x;
  const int w = tid >> 6;            // 0..7
  const int l = tid & 63;
  const int q5 = l & 31;             // this lane's q-row (within wave tile)
  const int h = l >> 5;              // half-wave
  const int nbase = qt * 256 + w * 32;

  const char* kgbase = (const char*)(kb + ((size_t)b * N_DIM) * CT_DIM);
  const char* vgbase = (const char*)(vtb + ((size_t)b * CT_DIM) * N_DIM);
  const int m_begin = s * (N_DIM / SPLIT);
  const int NT = (N_DIM / SPLIT) / KVBLK;  // 32

  // Q as B-operand fragments: lane needs Q[qrow][kk*16 + h*8 + 0..7]
  bf16x8 qf[16];
  {
    const short* qrow = qb + ((size_t)(b * N_DIM) + nbase + q5) * CT_DIM + h * 8;
#pragma unroll
    for (int kk = 0; kk < 16; ++kk)
      qf[kk] = *reinterpret_cast<const bf16x8*>(qrow + kk * 16);
  }

  f32x16 z16;
#pragma unroll
  for (int r = 0; r < 16; ++r) z16[r] = 0.f;
  f32x16 o8[8];  // O[q(reg,h)][ctg*32 + q5]
#pragma unroll
  for (int g = 0; g < 8; ++g) o8[g] = z16;
  float m_r = -1e30f, l_r = 0.f;

  const int ksw = (q5 & 15) << 3;

  auto stage = [&](int m0, int buf) {
    const char* ks = kgbase + (size_t)m0 * 512;  // 32 rows x 512B contiguous
#pragma unroll
    for (int i = 0; i < 2; ++i)
      gload16(ks + (w * 2 + i) * 1024 + l * 16,
              (char*)klds[buf] + (w * 2 + i) * 1024);
#pragma unroll
    for (int i = 0; i < 2; ++i) {
      const int base_ct = (w * 2 + i) * 16;
      gload16(vgbase + ((size_t)(base_ct + (l >> 2)) * N_DIM + m0) * 2 + (l & 3) * 16,
              (char*)vlds[buf] + base_ct * 64);
    }
  };

  auto compute = [&](int cur) {
    // ---- S^T = K Q : lane holds S[key(reg,h)][q5], keys = (reg&3)+8*(reg>>2)+4h ----
    f32x16 sacc = z16;
    __builtin_amdgcn_s_setprio(1);
#pragma unroll
    for (int kk = 0; kk < 16; ++kk) {
      bf16x8 kf = *reinterpret_cast<const bf16x8*>(
          &klds[cur][q5 * 256 + ((kk * 16 + h * 8) ^ ksw)]);
      sacc = MFMA32(kf, qf[kk], sacc);
    }
    __builtin_amdgcn_s_setprio(0);

    // ---- in-lane softmax ----
    float t0 = fmaxf(fmaxf(fmaxf(sacc[0], sacc[1]), fmaxf(sacc[2], sacc[3])),
                     fmaxf(fmaxf(sacc[4], sacc[5]), fmaxf(sacc[6], sacc[7])));
    float t1 = fmaxf(fmaxf(fmaxf(sacc[8], sacc[9]), fmaxf(sacc[10], sacc[11])),
                     fmaxf(fmaxf(sacc[12], sacc[13]), fmaxf(sacc[14], sacc[15])));
    float pmax = fmaxf(t0, t1);
    pmax = fmaxf(pmax, __shfl_xor(pmax, 32));

    const bool need = (bool)__any(pmax > m_r);
    float corr = 1.0f;
    if (need) {
      const float mnew = fmaxf(m_r, pmax);
      corr = __expf(m_r - mnew);
      m_r = mnew;
    }
    float rsum = 0.f;
#pragma unroll
    for (int r = 0; r < 16; ++r) {
      const float p = __expf(sacc[r] - m_r);
      sacc[r] = p;
      rsum += p;
    }
    rsum += __shfl_xor(rsum, 32);
    if (need) {
      l_r = l_r * corr + rsum;
      // rescale O: per reg, q = (reg&3)+8*(reg>>2)+4h; corr lives at lane q
#pragma unroll
      for (int reg = 0; reg < 16; ++reg) {
        const float cf = __shfl(corr, (reg & 3) + 8 * (reg >> 2) + 4 * h);
#pragma unroll
        for (int g = 0; g < 8; ++g) o8[g][reg] *= cf;
      }
    } else {
      l_r += rsum;
    }

    // ---- P -> A-operand fragments (in-register, one shfl pair per k-step) ----
    bf16x8 pa[2];
#pragma unroll
    for (int step = 0; step < 2; ++step) {
      const u32 pA0 = pack2(sacc[8 * step + 0], sacc[8 * step + 1]);
      const u32 pA1 = pack2(sacc[8 * step + 2], sacc[8 * step + 3]);
      const u32 pB0 = pack2(sacc[8 * step + 4], sacc[8 * step + 5]);
      const u32 pB1 = pack2(sacc[8 * step + 6], sacc[8 * step + 7]);
      const u32 loc0 = h ? pB0 : pA0;
      const u32 loc1 = h ? pB1 : pA1;
      const u32 rem0 = h ? pA0 : pB0;
      const u32 rem1 = h ? pA1 : pB1;
      const u32 g0 = __shfl_xor(rem0, 32);
      const u32 g1 = __shfl_xor(rem1, 32);
      struct W4 { u32 a, b, c, d; };
      W4 wv;
      wv.a = h ? g0 : loc0;
      wv.b = h ? g1 : loc1;
      wv.c = h ? loc0 : g0;
      wv.d = h ? loc1 : g1;
      pa[step] = __builtin_bit_cast(bf16x8, wv);
    }

    // ---- O += P V ----
    __builtin_amdgcn_s_setprio(1);
#pragma unroll
    for (int step = 0; step < 2; ++step) {
#pragma unroll
      for (int g = 0; g < 8; ++g) {
        const int ct = g * 32 + q5;
        bf16x8 vf = *reinterpret_cast<const bf16x8*>(
            &vlds[cur][ct * KVBLK + ((step * 16 + h * 8) ^ ((ct & 3) << 3))]);
        o8[g] = MFMA32(pa[step], vf, o8[g]);
      }
    }
    __builtin_amdgcn_s_setprio(0);
  };

  // ---- main loop: 1 barrier per iter, triple buffer, distance-1 prefetch ----
  stage(m_begin, 0);
  int cur = 0;
#pragma unroll 1
  for (int t = 0; t < NT; ++t) {
    if (t + 1 < NT) {
      stage(m_begin + (t + 1) * KVBLK, cur == 2 ? 0 : cur + 1);
      asm volatile("s_waitcnt vmcnt(4)" ::: "memory");
    } else {
      asm volatile("s_waitcnt vmcnt(0)" ::: "memory");
    }
    __builtin_amdgcn_s_barrier();
    __builtin_amdgcn_sched_barrier(0);
    compute(cur);
    cur = (cur == 2) ? 0 : cur + 1;
  }

  // ---- write partials: Opart[s][b][n][ct] bf16 ----
  short* ob = Opart + (size_t)(s * B_DIM + b) * N_DIM * CT_DIM;
#pragma unroll
  for (int reg = 0; reg < 16; ++reg) {
    const int n = nbase + (reg & 3) + 8 * (reg >> 2) + 4 * h;
#pragma unroll
    for (int g = 0; g < 8; ++g)
      ob[(size_t)n * CT_DIM + g * 32 + q5] = f2bf(o8[g][reg]);
  }
  if (l < 32) {
    const int n = nbase + q5;
    mpart[(size_t)(s * B_DIM + b) * N_DIM + n] = m_r;
    lpart[(size_t)(s * B_DIM + b) * N_DIM + n] = l_r;
  }
}

// Kernel 3: combine SPLIT partials -> ctxT bf16 (B, N, CT). grid = B*N, block = 256.
__global__ __launch_bounds__(256) void combine_kernel(
    const short* __restrict__ Opart, const float* __restrict__ mpart,
    const float* __restrict__ lpart, short* __restrict__ ctxT) {
  const int b = blockIdx.x >> 12;
  const int n = blockIdx.x & (N_DIM - 1);
  const int ct = threadIdx.x;
  const size_t row = (size_t)b * N_DIM + n;
  const size_t sstride = (size_t)B_DIM * N_DIM;
  float mv[SPLIT], lv[SPLIT];
  float mm = -1e30f;
#pragma unroll
  for (int s2 = 0; s2 < SPLIT; ++s2) {
    mv[s2] = mpart[s2 * sstride + row];
    lv[s2] = lpart[s2 * sstride + row];
    mm = fmaxf(mm, mv[s2]);
  }
  float L = 0.f, val = 0.f;
#pragma unroll
  for (int s2 = 0; s2 < SPLIT; ++s2) {
    const float e = __expf(mv[s2] - mm);
    L += e * lv[s2];
    val += e * bf2f(Opart[(s2 * sstride + row) * CT_DIM + ct]);
  }
  ctxT[row * CT_DIM + ct] = f2bf(val / L);
}

// Kernel 4: out[b][o][n] = Wo[:, :256] @ ctx + Wo[:, 256:] @ x. grid = B*(N/64), block=256.
__global__ __launch_bounds__(256) void out_kernel(
    const float* __restrict__ Wo, const short* __restrict__ ctxT,
    const short* __restrict__ xT, float* __restrict__ out) {
  const int b = blockIdx.x >> 6;
  const int n0 = (blockIdx.x & 63) * 64;
  const int tid = threadIdx.x;
  const int w = tid >> 6;
  const int l = tid & 63;
  const int lr = l & 15;
  const int lg = l >> 4;

  f32x4 zz; zz[0] = 0.f; zz[1] = 0.f; zz[2] = 0.f; zz[3] = 0.f;
  f32x4 acc[4][4];  // [os][ns]; wave w owns o range [w*64, w*64+64)
#pragma unroll
  for (int os = 0; os < 4; ++os)
#pragma unroll
    for (int ns = 0; ns < 4; ++ns) acc[os][ns] = zz;

#pragma unroll 4
  for (int kk = 0; kk < 16; ++kk) {
    const short* src = (kk < 8) ? ctxT : xT;
    const int c = (kk & 7) * 32 + lg * 8;
    bf16x8 bf[4], af[4];
#pragma unroll
    for (int ns = 0; ns < 4; ++ns)
      bf[ns] = *reinterpret_cast<const bf16x8*>(&src[((size_t)(b * N_DIM) + n0 + ns * 16 + lr) * 256 + c]);
#pragma unroll
    for (int os = 0; os < 4; ++os)
      af[os] = ldW8(&Wo[(size_t)(w * 64 + os * 16 + lr) * 512 + kk * 32 + lg * 8]);
#pragma unroll
    for (int os = 0; os < 4; ++os)
#pragma unroll
      for (int ns = 0; ns < 4; ++ns) acc[os][ns] = MFMA(af[os], bf[ns], acc[os][ns]);
  }

#pragma unroll
  for (int os = 0; os < 4; ++os)
#pragma unroll
    for (int ns = 0; ns < 4; ++ns)
#pragma unroll
      for (int r = 0; r < 4; ++r) {
        const int oo = w * 64 + os * 16 + lg * 4 + r;
        const int n = n0 + ns * 16 + lr;
        out[((size_t)(b * C_DIM) + oo) * N_DIM + n] = acc[os][ns][r];
      }
}

extern "C" void kernel_launch(void* const* d_in, const int* in_sizes, int n_in,
                              void* d_out, int out_size, void* d_ws, size_t ws_size,
                              hipStream_t stream) {
  const float* x = (const float*)d_in[0];
  const float* Wq = (const float*)d_in[1];
  const float* Wk = (const float*)d_in[2];
  const float* Wv = (const float*)d_in[3];
  const float* Wo = (const float*)d_in[4];
  float* out = (float*)d_out;

  char* ws = (char*)d_ws;
  const size_t SZ_BNCT = (size_t)B_DIM * N_DIM * CT_DIM * sizeof(short);  // 8 MB
  short* qb   = (short*)(ws);
  short* kb   = (short*)(ws + SZ_BNCT);
  short* vtb  = (short*)(ws + 2 * SZ_BNCT);
  short* xT   = (short*)(ws + 3 * SZ_BNCT);
  short* ctxT = (short*)(ws + 4 * SZ_BNCT);
  short* Opart = (short*)(ws + 5 * SZ_BNCT);  // SPLIT * B * N * CT bf16 = 32 MB
  float* mpart = (float*)(ws + 5 * SZ_BNCT + (size_t)SPLIT * B_DIM * N_DIM * CT_DIM * sizeof(short));
  float* lpart = mpart + (size_t)SPLIT * B_DIM * N_DIM;

  proj_kernel<<<B_DIM * (N_DIM / 64), 256, 0, stream>>>(x, Wq, Wk, Wv, qb, kb, vtb, xT);
  attn_kernel<<<B_DIM * (N_DIM / 256) * SPLIT, 512, 0, stream>>>(qb, kb, vtb, Opart, mpart, lpart);
  combine_kernel<<<B_DIM * N_DIM, 256, 0, stream>>>(Opart, mpart, lpart, ctxT);
  out_kernel<<<B_DIM * (N_DIM / 64), 256, 0, stream>>>(Wo, ctxT, xT, out);
}